// Round 1
// baseline (211.110 us; speedup 1.0000x reference)
//
#include <hip/hip_runtime.h>

#define NQKV (128*4*512*8)   // 2,097,152 floats per q/k/v buffer

__device__ __forceinline__ float elu1(float x) { return x > 0.f ? x : expm1f(x); }

// ---------------------------------------------------------------------------
// K1: LayerNorm(x_path) then QKV projection into head-separated layout
//     q/k/v: [B, H, S, 8].  Block = 256 threads handles 8 rows.
// ---------------------------------------------------------------------------
__global__ __launch_bounds__(256) void k_ln_qkv(
    const float* __restrict__ xp, const float* __restrict__ ln_g, const float* __restrict__ ln_b,
    const float* __restrict__ Wqkv, const float* __restrict__ bqkv,
    float* __restrict__ q, float* __restrict__ k, float* __restrict__ v)
{
  __shared__ float WT[32][96];   // WT[e][c] = Wqkv[c][e] (transposed: conflict-free reads)
  __shared__ float bsh[96];
  __shared__ float xn[8][32];
  int tid = threadIdx.x;
  for (int i = tid; i < 96 * 32; i += 256) WT[i & 31][i >> 5] = Wqkv[i];
  if (tid < 96) bsh[tid] = bqkv[tid];

  int g = tid >> 5, e = tid & 31;
  int row = blockIdx.x * 8 + g;
  float x = xp[row * 32 + e];
  float s1 = x, s2 = x * x;
  #pragma unroll
  for (int m = 16; m >= 1; m >>= 1) { s1 += __shfl_xor(s1, m, 32); s2 += __shfl_xor(s2, m, 32); }
  float mu  = s1 * 0.03125f;
  float var = s2 * 0.03125f - mu * mu;
  xn[g][e] = (x - mu) * rsqrtf(var + 1e-5f) * ln_g[e] + ln_b[e];
  __syncthreads();

  #pragma unroll
  for (int p = 0; p < 3; ++p) {
    int o = tid + p * 256;
    int r = o / 96, c = o - r * 96;
    float acc = bsh[c];
    const float* xr = xn[r];
    #pragma unroll
    for (int ee = 0; ee < 32; ++ee) acc += xr[ee] * WT[ee][c];
    int rowg = blockIdx.x * 8 + r;
    int b = rowg >> 9, s = rowg & 511;
    int cc = c & 31;
    float* dst = (c < 32) ? q : (c < 64 ? k : v);
    dst[(((b << 2) + (cc >> 3)) * 512 + s) * 8 + (cc & 7)] = acc;
  }
}

// ---------------------------------------------------------------------------
// K2: per-(b,h) attention.  512 blocks x 256 threads; k/v staged in LDS,
//     wave-uniform broadcast reads; 2 query rows per thread; no-max online
//     softmax (scores bounded; clamped).  Output written back INTO the q
//     buffer (thread-private rows -> safe alias), layout [B,H,S,8].
// ---------------------------------------------------------------------------
__global__ __launch_bounds__(256) void k_attn(
    float* qo, const float* __restrict__ k, const float* __restrict__ v)
{
  __shared__ float ks[4096];
  __shared__ float vs[4096];
  int bh = blockIdx.x;
  int tid = threadIdx.x;
  const float* kb = k + bh * 4096;
  const float* vb = v + bh * 4096;
  for (int i = tid; i < 1024; i += 256) {
    ((float4*)ks)[i] = ((const float4*)kb)[i];
    ((float4*)vs)[i] = ((const float4*)vb)[i];
  }
  __syncthreads();

  float* qb = qo + bh * 4096;
  int r0 = tid, r1 = tid + 256;
  float4 qa0 = ((const float4*)qb)[r0 * 2], qb0 = ((const float4*)qb)[r0 * 2 + 1];
  float4 qa1 = ((const float4*)qb)[r1 * 2], qb1 = ((const float4*)qb)[r1 * 2 + 1];
  const float sc = 0.35355339059327373f;  // 1/sqrt(8)
  float q0[8] = {qa0.x*sc, qa0.y*sc, qa0.z*sc, qa0.w*sc, qb0.x*sc, qb0.y*sc, qb0.z*sc, qb0.w*sc};
  float q1[8] = {qa1.x*sc, qa1.y*sc, qa1.z*sc, qa1.w*sc, qb1.x*sc, qb1.y*sc, qb1.z*sc, qb1.w*sc};
  float acc0[8] = {}, acc1[8] = {};
  float l0 = 0.f, l1 = 0.f;

  #pragma unroll 2
  for (int kk = 0; kk < 512; ++kk) {
    float4 ka = ((float4*)ks)[kk * 2], kc = ((float4*)ks)[kk * 2 + 1];
    float4 va = ((float4*)vs)[kk * 2], vc = ((float4*)vs)[kk * 2 + 1];
    float kf[8] = {ka.x, ka.y, ka.z, ka.w, kc.x, kc.y, kc.z, kc.w};
    float vf[8] = {va.x, va.y, va.z, va.w, vc.x, vc.y, vc.z, vc.w};
    float s0 = 0.f, s1 = 0.f;
    #pragma unroll
    for (int j = 0; j < 8; ++j) { s0 += q0[j] * kf[j]; s1 += q1[j] * kf[j]; }
    float p0 = __expf(fminf(s0, 80.f));
    float p1 = __expf(fminf(s1, 80.f));
    l0 += p0; l1 += p1;
    #pragma unroll
    for (int j = 0; j < 8; ++j) { acc0[j] += p0 * vf[j]; acc1[j] += p1 * vf[j]; }
  }
  float i0 = 1.f / l0, i1 = 1.f / l1;
  float4 oa0 = {acc0[0]*i0, acc0[1]*i0, acc0[2]*i0, acc0[3]*i0};
  float4 ob0 = {acc0[4]*i0, acc0[5]*i0, acc0[6]*i0, acc0[7]*i0};
  float4 oa1 = {acc1[0]*i1, acc1[1]*i1, acc1[2]*i1, acc1[3]*i1};
  float4 ob1 = {acc1[4]*i1, acc1[5]*i1, acc1[6]*i1, acc1[7]*i1};
  ((float4*)qb)[r0 * 2] = oa0; ((float4*)qb)[r0 * 2 + 1] = ob0;
  ((float4*)qb)[r1 * 2] = oa1; ((float4*)qb)[r1 * 2 + 1] = ob1;
}

// ---------------------------------------------------------------------------
// K3: out-projection + residual: img[b,s,:] = x_path[b,s,:] + o @ Wo^T + bo
//     o is in [B,H,S,8] layout (aliased q buffer).
// ---------------------------------------------------------------------------
__global__ __launch_bounds__(256) void k_oproj(
    const float* __restrict__ o, const float* __restrict__ xp,
    const float* __restrict__ Wo, const float* __restrict__ bo,
    float* __restrict__ img)
{
  __shared__ float WoT[32][32];  // WoT[e'][e] = Wo[e][e']
  __shared__ float bos[32];
  __shared__ float orow[8][32];
  int tid = threadIdx.x;
  for (int i = tid; i < 1024; i += 256) WoT[i & 31][i >> 5] = Wo[i];
  if (tid < 32) bos[tid] = bo[tid];

  int g = tid >> 5, e = tid & 31;
  int row = blockIdx.x * 8 + g;
  int b = row >> 9, s = row & 511;
  orow[g][e] = o[(((b << 2) + (e >> 3)) * 512 + s) * 8 + (e & 7)];
  __syncthreads();

  float acc = bos[e];
  const float* orr = orow[g];
  #pragma unroll
  for (int ee = 0; ee < 32; ++ee) acc += orr[ee] * WoT[ee][e];
  img[row * 32 + e] = xp[row * 32 + e] + acc;
}

// ---------------------------------------------------------------------------
// K4: everything else.  Layers 0..10 are dead code (qo-attention with a
//     single key ignores its query input => each layer depends only on
//     omic_emb, img, and that layer's weights).  Only layer 11 matters.
//     One block per batch element.
// ---------------------------------------------------------------------------
__global__ __launch_bounds__(256) void k_final(
    const float* __restrict__ img, const float* __restrict__ xo,
    const float* __restrict__ oW0, const float* __restrict__ ob0,
    const float* __restrict__ oW1, const float* __restrict__ ob1,
    const float* __restrict__ oW2, const float* __restrict__ ob2,
    const float* __restrict__ oW3, const float* __restrict__ ob3,
    const float* __restrict__ qoW, const float* __restrict__ qob,
    const float* __restrict__ qoWo, const float* __restrict__ qobo,
    const float* __restrict__ qpW, const float* __restrict__ qpb,
    const float* __restrict__ qpWo, const float* __restrict__ qpbo,
    const float* __restrict__ fW1, const float* __restrict__ fb1,
    const float* __restrict__ fW2, const float* __restrict__ fb2,
    const float* __restrict__ gW, const float* __restrict__ gb,
    const float* __restrict__ hW, const float* __restrict__ hb,
    float* __restrict__ out)
{
  __shared__ float p[4][512];
  __shared__ float partial[8][4][32];
  __shared__ float buf1[80], buf2[64];
  __shared__ float emb[32], qbar[32], qh[32], u[4][32], cc4[4], lsum[4], ctx4[4][32], t32[32], o32[32];
  int b = blockIdx.x, tid = threadIdx.x;

  // ---- frozen omic encoder: 80 -> 64 -> 48 -> 32 -> 32, ELU each ----
  if (tid < 80) buf1[tid] = xo[b * 80 + tid];
  __syncthreads();
  if (tid < 64) { float a = ob0[tid]; const float* w = oW0 + tid * 80;
    for (int e = 0; e < 80; ++e) a += buf1[e] * w[e]; buf2[tid] = elu1(a); }
  __syncthreads();
  if (tid < 48) { float a = ob1[tid]; const float* w = oW1 + tid * 64;
    for (int e = 0; e < 64; ++e) a += buf2[e] * w[e]; buf1[tid] = elu1(a); }
  __syncthreads();
  if (tid < 32) { float a = ob2[tid]; const float* w = oW2 + tid * 48;
    for (int e = 0; e < 48; ++e) a += buf1[e] * w[e]; buf2[tid] = elu1(a); }
  __syncthreads();
  if (tid < 32) { float a = ob3[tid]; const float* w = oW3 + tid * 32;
    for (int e = 0; e < 32; ++e) a += buf2[e] * w[e]; emb[tid] = elu1(a); }
  __syncthreads();

  // ---- qo attention, kv-len 1: softmax==1 => o = Wv*emb + bv, then Wo ----
  if (tid < 32) { float a = qob[64 + tid]; const float* w = qoW + (64 + tid) * 32;
    for (int e = 0; e < 32; ++e) a += emb[e] * w[e]; t32[tid] = a; }
  __syncthreads();
  if (tid < 32) { float a = qobo[tid]; const float* w = qoWo + tid * 32;
    for (int e = 0; e < 32; ++e) a += t32[e] * w[e]; qbar[tid] = a; }
  __syncthreads();

  // ---- qp attention with a single query row (folded Wk / Wv) ----
  if (tid < 32) { float a = qpb[tid]; const float* w = qpW + tid * 32;
    for (int e = 0; e < 32; ++e) a += qbar[e] * w[e]; qh[tid] = a; }
  __syncthreads();
  if (tid < 128) {
    int h = tid >> 5, e = tid & 31;
    float a = 0.f;
    #pragma unroll
    for (int d = 0; d < 8; ++d) a += qh[h * 8 + d] * qpW[(32 + h * 8 + d) * 32 + e];
    u[h][e] = a;
    if (e == 0) { float c2 = 0.f; for (int d = 0; d < 8; ++d) c2 += qh[h * 8 + d] * qpb[32 + h * 8 + d]; cc4[h] = c2; }
  }
  __syncthreads();

  const float* ibase = img + b * 16384;
  #pragma unroll
  for (int j = 0; j < 8; ++j) {
    int idx = tid + j * 256; int h = idx >> 9, kk = idx & 511;
    const float4* ir = (const float4*)(ibase + kk * 32);
    const float* uh = u[h];
    float a = cc4[h];
    #pragma unroll
    for (int e4 = 0; e4 < 8; ++e4) {
      float4 t = ir[e4];
      a += uh[e4 * 4] * t.x + uh[e4 * 4 + 1] * t.y + uh[e4 * 4 + 2] * t.z + uh[e4 * 4 + 3] * t.w;
    }
    p[h][kk] = __expf(fminf(a * 0.35355339059327373f, 80.f));
  }
  __syncthreads();
  {
    int w = tid >> 6, lane = tid & 63;
    float a = 0.f;
    for (int kk = lane; kk < 512; kk += 64) a += p[w][kk];
    #pragma unroll
    for (int m = 32; m >= 1; m >>= 1) a += __shfl_xor(a, m, 64);
    if (lane == 0) lsum[w] = 1.f / a;
  }
  {
    int e = tid & 31, ch = tid >> 5;
    float a0 = 0.f, a1 = 0.f, a2 = 0.f, a3 = 0.f;
    for (int kk = ch * 64; kk < ch * 64 + 64; ++kk) {
      float val = ibase[kk * 32 + e];
      a0 += p[0][kk] * val; a1 += p[1][kk] * val; a2 += p[2][kk] * val; a3 += p[3][kk] * val;
    }
    partial[ch][0][e] = a0; partial[ch][1][e] = a1; partial[ch][2][e] = a2; partial[ch][3][e] = a3;
  }
  __syncthreads();
  if (tid < 128) {
    int h = tid >> 5, e = tid & 31;
    float a = 0.f;
    #pragma unroll
    for (int ch = 0; ch < 8; ++ch) a += partial[ch][h][e];
    ctx4[h][e] = a * lsum[h];
  }
  __syncthreads();
  if (tid < 32) { int h = tid >> 3;
    float a = qpb[64 + tid]; const float* w = qpW + (64 + tid) * 32;
    for (int e = 0; e < 32; ++e) a += ctx4[h][e] * w[e]; o32[tid] = a; }
  __syncthreads();
  if (tid < 32) { float a = qpbo[tid]; const float* w = qpWo + tid * 32;
    for (int e = 0; e < 32; ++e) a += o32[e] * w[e]; t32[tid] = a; }
  __syncthreads();

  // ---- FFN (no residual) ----
  if (tid < 32) { float a = fb1[tid]; const float* w = fW1 + tid * 32;
    for (int e = 0; e < 32; ++e) a += t32[e] * w[e]; o32[tid] = fmaxf(a, 0.f); }
  __syncthreads();
  if (tid < 32) { float a = fb2[tid]; const float* w = fW2 + tid * 32;
    for (int e = 0; e < 32; ++e) a += o32[e] * w[e]; qbar[tid] = a; }
  __syncthreads();

  // ---- heads ----
  if (tid < 32) out[b * 32 + tid] = qbar[tid];
  if (tid == 0) {
    float g0 = gb[0], g1 = gb[1], g2 = gb[2];
    for (int e = 0; e < 32; ++e) { float f = qbar[e]; g0 += f * gW[e]; g1 += f * gW[32 + e]; g2 += f * gW[64 + e]; }
    float m = fmaxf(g0, fmaxf(g1, g2));
    float lse = m + logf(expf(g0 - m) + expf(g1 - m) + expf(g2 - m));
    float* og = out + 4096;
    og[b * 3 + 0] = g0 - lse; og[b * 3 + 1] = g1 - lse; og[b * 3 + 2] = g2 - lse;
    float hz = hb[0];
    for (int e = 0; e < 32; ++e) hz += qbar[e] * hW[e];
    out[4480 + b] = 1.f / (1.f + expf(-hz)) * 6.f - 3.f;
  }
}

extern "C" void kernel_launch(void* const* d_in, const int* in_sizes, int n_in,
                              void* d_out, int out_size, void* d_ws, size_t ws_size,
                              hipStream_t stream) {
  const float* x_omic = (const float*)d_in[0];
  const float* x_path = (const float*)d_in[1];
  const float* oW0 = (const float*)d_in[2];  const float* ob0 = (const float*)d_in[3];
  const float* oW1 = (const float*)d_in[4];  const float* ob1 = (const float*)d_in[5];
  const float* oW2 = (const float*)d_in[6];  const float* ob2 = (const float*)d_in[7];
  const float* oW3 = (const float*)d_in[8];  const float* ob3 = (const float*)d_in[9];
  const float* ln_g = (const float*)d_in[10]; const float* ln_b = (const float*)d_in[11];
  const float* cW  = (const float*)d_in[12]; const float* cb  = (const float*)d_in[13];
  const float* cWo = (const float*)d_in[14]; const float* cbo = (const float*)d_in[15];
  const float* qoW = (const float*)d_in[16]; const float* qob = (const float*)d_in[17];
  const float* qoWo = (const float*)d_in[18]; const float* qobo = (const float*)d_in[19];
  const float* qpW = (const float*)d_in[20]; const float* qpb = (const float*)d_in[21];
  const float* qpWo = (const float*)d_in[22]; const float* qpbo = (const float*)d_in[23];
  const float* fW1 = (const float*)d_in[24]; const float* fb1 = (const float*)d_in[25];
  const float* fW2 = (const float*)d_in[26]; const float* fb2 = (const float*)d_in[27];
  // d_in[28] = Qs — provably unused (qo attention ignores its query input)
  const float* gW = (const float*)d_in[29]; const float* gb = (const float*)d_in[30];
  const float* hW = (const float*)d_in[31]; const float* hb = (const float*)d_in[32];

  float* out = (float*)d_out;
  float* ws = (float*)d_ws;
  float* q    = ws;             // [B,H,S,8]
  float* kbuf = ws + NQKV;      // [B,H,S,8]
  float* vbuf = ws + 2 * NQKV;  // [B,H,S,8]
  float* o    = q;              // attn output aliases q (thread-private rows)
  float* img  = kbuf;           // img aliases k (k dead after k_attn)

  const int L = 11;  // layers 0..10 are dead code
  k_ln_qkv<<<8192, 256, 0, stream>>>(x_path, ln_g, ln_b, cW, cb, q, kbuf, vbuf);
  k_attn<<<512, 256, 0, stream>>>(q, kbuf, vbuf);
  k_oproj<<<8192, 256, 0, stream>>>(o, x_path, cWo, cbo, img);
  k_final<<<128, 256, 0, stream>>>(img, x_omic,
      oW0, ob0, oW1, ob1, oW2, ob2, oW3, ob3,
      qoW + L * 96 * 32, qob + L * 96, qoWo + L * 32 * 32, qobo + L * 32,
      qpW + L * 96 * 32, qpb + L * 96, qpWo + L * 32 * 32, qpbo + L * 32,
      fW1 + L * 32 * 32, fb1 + L * 32, fW2 + L * 32 * 32, fb2 + L * 32,
      gW, gb, hW, hb, out);
}

// Round 2
// 195.203 us; speedup vs baseline: 1.0815x; 1.0815x over previous
//
#include <hip/hip_runtime.h>
#include <hip/hip_bf16.h>

#define NQKV (128*4*512*8)   // 2,097,152 elements per q/k/v tensor

typedef __attribute__((ext_vector_type(8))) short short8;
typedef __attribute__((ext_vector_type(4))) float f32x4;

__device__ __forceinline__ float elu1(float x) { return x > 0.f ? x : expm1f(x); }
__device__ __forceinline__ unsigned pkbf(float a, float b) {
  return (unsigned)__bfloat16_as_ushort(__float2bfloat16(a)) |
         ((unsigned)__bfloat16_as_ushort(__float2bfloat16(b)) << 16);
}
__device__ __forceinline__ float bfu(unsigned u) { return __uint_as_float(u << 16); }

// ---------------------------------------------------------------------------
// K1: LayerNorm(x_path) -> QKV proj -> bf16 outputs.
//     q (pre-scaled by 1/sqrt(8)) and k in [B,H,S,8]; v transposed [B,H,8,S].
//     Block = 256 threads handles 8 consecutive rows s.
// ---------------------------------------------------------------------------
__global__ __launch_bounds__(256) void k_ln_qkv(
    const float* __restrict__ xp, const float* __restrict__ ln_g, const float* __restrict__ ln_b,
    const float* __restrict__ Wqkv, const float* __restrict__ bqkv,
    ushort* __restrict__ qbf, ushort* __restrict__ kbf, ushort* __restrict__ vtbf)
{
  __shared__ float WT[32][96];   // WT[e][c] = Wqkv[c][e]
  __shared__ float bsh[96];
  __shared__ float xn[8][32];
  __shared__ float qkv[8][96];
  int tid = threadIdx.x;
  for (int i = tid; i < 96 * 32; i += 256) WT[i & 31][i >> 5] = Wqkv[i];
  if (tid < 96) bsh[tid] = bqkv[tid];

  int g = tid >> 5, e = tid & 31;
  int row = blockIdx.x * 8 + g;
  float x = xp[row * 32 + e];
  float s1 = x, s2 = x * x;
  #pragma unroll
  for (int m = 16; m >= 1; m >>= 1) { s1 += __shfl_xor(s1, m, 32); s2 += __shfl_xor(s2, m, 32); }
  float mu  = s1 * 0.03125f;
  float var = s2 * 0.03125f - mu * mu;
  xn[g][e] = (x - mu) * rsqrtf(var + 1e-5f) * ln_g[e] + ln_b[e];
  __syncthreads();

  #pragma unroll
  for (int p = 0; p < 3; ++p) {
    int o = tid + p * 256;
    int r = o / 96, c = o - r * 96;
    float acc = bsh[c];
    const float* xr = xn[r];
    #pragma unroll
    for (int ee = 0; ee < 32; ++ee) acc += xr[ee] * WT[ee][c];
    qkv[r][c] = acc;
  }
  __syncthreads();

  // q/k: 256 threads -> 256 packed dword stores
  {
    const float sc = 0.35355339059327373f;  // fold 1/sqrt(8) into q
    int which = tid >> 7;           // 0: q, 1: k
    int r = (tid >> 4) & 7, h = (tid >> 2) & 3, pr = tid & 3;
    int cbase = which * 32 + h * 8 + pr * 2;
    float v0 = qkv[r][cbase], v1 = qkv[r][cbase + 1];
    if (which == 0) { v0 *= sc; v1 *= sc; }
    int s = blockIdx.x * 8 + r; int b = s >> 9; s &= 511;
    unsigned* dst = (unsigned*)(which ? kbf : qbf);
    dst[((b * 4 + h) * 512 + s) * 4 + pr] = pkbf(v0, v1);
  }
  // v^T: threads 0-31, one b128 each (8 consecutive s per channel)
  if (tid < 32) {
    int h = tid >> 3, d = tid & 7;
    float v[8];
    #pragma unroll
    for (int s8 = 0; s8 < 8; ++s8) v[s8] = qkv[s8][64 + tid];
    uint4 o4 = { pkbf(v[0], v[1]), pkbf(v[2], v[3]), pkbf(v[4], v[5]), pkbf(v[6], v[7]) };
    int s0 = blockIdx.x * 8; int b = s0 >> 9; int sl = s0 & 511;
    unsigned* dst = (unsigned*)vtbf + (((b * 4 + h) * 8 + d) * 512 + sl) / 2;
    *(uint4*)dst = o4;
  }
}

// ---------------------------------------------------------------------------
// K2: MFMA attention per (b,h).  Block = 512 threads (8 waves, 64 rows each).
//     S^T = K.Q^T via 16x16x32 bf16 (d=8 of K=32 used, zero-padded lanes);
//     exp'd P written to per-wave-private LDS (stride 136: <=2-way conflicts);
//     O^T = V^T.P^T with full K=32 utilization, V-frags resident in VGPRs.
//     No-max softmax (scores bounded); fp32 row-sum; bf16 O out.
// ---------------------------------------------------------------------------
__global__ __launch_bounds__(512, 4) void k_attn(
    const ushort* __restrict__ qbf, const ushort* __restrict__ kbf,
    const ushort* __restrict__ vtbf, ushort* __restrict__ obf)
{
  __shared__ ushort ks[512 * 8];        // K  [s][d] bf16, 8KB
  __shared__ ushort vts[8 * 512];       // V^T [d][s] bf16, 8KB
  __shared__ ushort ps[8][16 * 136];    // per-wave P [16 qrow][136 (128 kidx + pad)]
  int tid = threadIdx.x;
  int bh = blockIdx.x;
  ((uint4*)ks)[tid]  = ((const uint4*)kbf)[bh * 512 + tid];
  ((uint4*)vts)[tid] = ((const uint4*)vtbf)[bh * 512 + tid];
  __syncthreads();

  int w = tid >> 6, lane = tid & 63, g = lane >> 4, qr = lane & 15;
  const short8 z8 = {0, 0, 0, 0, 0, 0, 0, 0};

  // V-frags: vf[i] lane holds V^T[d=qr (d<8), kidx=i*32 + g*8 + j]
  short8 vf[16];
  bool vact = qr < 8;
  #pragma unroll
  for (int i = 0; i < 16; ++i)
    vf[i] = vact ? *(const short8*)(vts + qr * 512 + i * 32 + g * 8) : z8;

  ushort* pw = &ps[w][0];

  for (int qg = 0; qg < 4; ++qg) {
    int q0 = w * 64 + qg * 16;
    // B-frag: Q^T -> lane holds Q[qrow=qr, d=j] for g==0; zeros else
    short8 qf = (g == 0) ? *(const short8*)(qbf + (bh * 512 + q0 + qr) * 8) : z8;
    f32x4 ot = {0.f, 0.f, 0.f, 0.f};
    float lp = 0.f;

    for (int c = 0; c < 4; ++c) {
      #pragma unroll
      for (int t = 0; t < 8; ++t) {
        int krow = c * 128 + t * 16;
        // A-frag: K rows -> lane holds K[krow+qr, d=j] for g==0; zeros else
        short8 af = (g == 0) ? *(const short8*)(ks + (krow + qr) * 8) : z8;
        f32x4 s4 = __builtin_amdgcn_mfma_f32_16x16x32_bf16(af, qf, (f32x4){0.f,0.f,0.f,0.f}, 0, 0, 0);
        // lane holds S^T[kidx_local = t*16 + g*4 + r, qrow = qr]
        float e0 = __expf(s4[0]), e1 = __expf(s4[1]);
        float e2 = __expf(s4[2]), e3 = __expf(s4[3]);
        lp += (e0 + e1) + (e2 + e3);
        uint2 pk2 = { pkbf(e0, e1), pkbf(e2, e3) };
        *(uint2*)(pw + qr * 136 + t * 16 + g * 4) = pk2;
      }
      // PV for this 128-kidx chunk (K=32 per MFMA)
      #pragma unroll
      for (int tp = 0; tp < 4; ++tp) {
        short8 pb = *(const short8*)(pw + qr * 136 + tp * 32 + g * 8);
        ot = __builtin_amdgcn_mfma_f32_16x16x32_bf16(vf[c * 4 + tp], pb, ot, 0, 0, 0);
      }
    }
    // full row-sum for qrow=qr (partials live in 4 lane-groups)
    lp += __shfl_xor(lp, 16);
    lp += __shfl_xor(lp, 32);
    float rl = 1.f / lp;
    // O^T: lane holds O[qrow=qr, d=g*4+r], valid for g<2
    if (g < 2) {
      uint2 o2 = { pkbf(ot[0] * rl, ot[1] * rl), pkbf(ot[2] * rl, ot[3] * rl) };
      *(uint2*)((unsigned*)obf + (bh * 512 + q0 + qr) * 4 + g * 2) = o2;
    }
  }
}

// ---------------------------------------------------------------------------
// K3: out-projection + residual: img[b,s,:] = x_path[b,s,:] + o @ Wo^T + bo
//     o is bf16 in [B,H,S,8].
// ---------------------------------------------------------------------------
__global__ __launch_bounds__(256) void k_oproj(
    const ushort* __restrict__ obf, const float* __restrict__ xp,
    const float* __restrict__ Wo, const float* __restrict__ bo,
    float* __restrict__ img)
{
  __shared__ float WoT[32][32];  // WoT[e'][e] = Wo[e][e']
  __shared__ float bos[32];
  __shared__ float orow[8][32];
  int tid = threadIdx.x;
  for (int i = tid; i < 1024; i += 256) WoT[i & 31][i >> 5] = Wo[i];
  if (tid < 32) bos[tid] = bo[tid];
  if (tid < 64) {
    int r = tid >> 3, h = (tid >> 1) & 3, half = tid & 1;
    int s = blockIdx.x * 8 + r; int b = s >> 9; int sl = s & 511;
    uint2 u = *(const uint2*)((const unsigned*)obf + ((b * 4 + h) * 512 + sl) * 4 + half * 2);
    float* o4 = &orow[r][h * 8 + half * 4];
    o4[0] = bfu(u.x & 0xffffu); o4[1] = bfu(u.x >> 16);
    o4[2] = bfu(u.y & 0xffffu); o4[3] = bfu(u.y >> 16);
  }
  __syncthreads();

  int g = tid >> 5, e = tid & 31;
  int row = blockIdx.x * 8 + g;
  float acc = bos[e];
  const float* orr = orow[g];
  #pragma unroll
  for (int ee = 0; ee < 32; ++ee) acc += orr[ee] * WoT[ee][e];
  img[row * 32 + e] = xp[row * 32 + e] + acc;
}

// ---------------------------------------------------------------------------
// K4: everything else.  Layers 0..10 are dead code (qo-attention with a
//     single key ignores its query input).  Only layer 11 matters.
// ---------------------------------------------------------------------------
__global__ __launch_bounds__(256) void k_final(
    const float* __restrict__ img, const float* __restrict__ xo,
    const float* __restrict__ oW0, const float* __restrict__ ob0,
    const float* __restrict__ oW1, const float* __restrict__ ob1,
    const float* __restrict__ oW2, const float* __restrict__ ob2,
    const float* __restrict__ oW3, const float* __restrict__ ob3,
    const float* __restrict__ qoW, const float* __restrict__ qob,
    const float* __restrict__ qoWo, const float* __restrict__ qobo,
    const float* __restrict__ qpW, const float* __restrict__ qpb,
    const float* __restrict__ qpWo, const float* __restrict__ qpbo,
    const float* __restrict__ fW1, const float* __restrict__ fb1,
    const float* __restrict__ fW2, const float* __restrict__ fb2,
    const float* __restrict__ gW, const float* __restrict__ gb,
    const float* __restrict__ hW, const float* __restrict__ hb,
    float* __restrict__ out)
{
  __shared__ float p[4][512];
  __shared__ float partial[8][4][32];
  __shared__ float buf1[80], buf2[64];
  __shared__ float emb[32], qbar[32], qh[32], u[4][32], cc4[4], lsum[4], ctx4[4][32], t32[32], o32[32];
  int b = blockIdx.x, tid = threadIdx.x;

  if (tid < 80) buf1[tid] = xo[b * 80 + tid];
  __syncthreads();
  if (tid < 64) { float a = ob0[tid]; const float* w = oW0 + tid * 80;
    for (int e = 0; e < 80; ++e) a += buf1[e] * w[e]; buf2[tid] = elu1(a); }
  __syncthreads();
  if (tid < 48) { float a = ob1[tid]; const float* w = oW1 + tid * 64;
    for (int e = 0; e < 64; ++e) a += buf2[e] * w[e]; buf1[tid] = elu1(a); }
  __syncthreads();
  if (tid < 32) { float a = ob2[tid]; const float* w = oW2 + tid * 48;
    for (int e = 0; e < 48; ++e) a += buf1[e] * w[e]; buf2[tid] = elu1(a); }
  __syncthreads();
  if (tid < 32) { float a = ob3[tid]; const float* w = oW3 + tid * 32;
    for (int e = 0; e < 32; ++e) a += buf2[e] * w[e]; emb[tid] = elu1(a); }
  __syncthreads();

  if (tid < 32) { float a = qob[64 + tid]; const float* w = qoW + (64 + tid) * 32;
    for (int e = 0; e < 32; ++e) a += emb[e] * w[e]; t32[tid] = a; }
  __syncthreads();
  if (tid < 32) { float a = qobo[tid]; const float* w = qoWo + tid * 32;
    for (int e = 0; e < 32; ++e) a += t32[e] * w[e]; qbar[tid] = a; }
  __syncthreads();

  if (tid < 32) { float a = qpb[tid]; const float* w = qpW + tid * 32;
    for (int e = 0; e < 32; ++e) a += qbar[e] * w[e]; qh[tid] = a; }
  __syncthreads();
  if (tid < 128) {
    int h = tid >> 5, e = tid & 31;
    float a = 0.f;
    #pragma unroll
    for (int d = 0; d < 8; ++d) a += qh[h * 8 + d] * qpW[(32 + h * 8 + d) * 32 + e];
    u[h][e] = a;
    if (e == 0) { float c2 = 0.f; for (int d = 0; d < 8; ++d) c2 += qh[h * 8 + d] * qpb[32 + h * 8 + d]; cc4[h] = c2; }
  }
  __syncthreads();

  const float* ibase = img + b * 16384;
  #pragma unroll
  for (int j = 0; j < 8; ++j) {
    int idx = tid + j * 256; int h = idx >> 9, kk = idx & 511;
    const float4* ir = (const float4*)(ibase + kk * 32);
    const float* uh = u[h];
    float a = cc4[h];
    #pragma unroll
    for (int e4 = 0; e4 < 8; ++e4) {
      float4 t = ir[e4];
      a += uh[e4 * 4] * t.x + uh[e4 * 4 + 1] * t.y + uh[e4 * 4 + 2] * t.z + uh[e4 * 4 + 3] * t.w;
    }
    p[h][kk] = __expf(fminf(a * 0.35355339059327373f, 80.f));
  }
  __syncthreads();
  {
    int w = tid >> 6, lane = tid & 63;
    float a = 0.f;
    for (int kk = lane; kk < 512; kk += 64) a += p[w][kk];
    #pragma unroll
    for (int m = 32; m >= 1; m >>= 1) a += __shfl_xor(a, m, 64);
    if (lane == 0) lsum[w] = 1.f / a;
  }
  {
    int e = tid & 31, ch = tid >> 5;
    float a0 = 0.f, a1 = 0.f, a2 = 0.f, a3 = 0.f;
    for (int kk = ch * 64; kk < ch * 64 + 64; ++kk) {
      float val = ibase[kk * 32 + e];
      a0 += p[0][kk] * val; a1 += p[1][kk] * val; a2 += p[2][kk] * val; a3 += p[3][kk] * val;
    }
    partial[ch][0][e] = a0; partial[ch][1][e] = a1; partial[ch][2][e] = a2; partial[ch][3][e] = a3;
  }
  __syncthreads();
  if (tid < 128) {
    int h = tid >> 5, e = tid & 31;
    float a = 0.f;
    #pragma unroll
    for (int ch = 0; ch < 8; ++ch) a += partial[ch][h][e];
    ctx4[h][e] = a * lsum[h];
  }
  __syncthreads();
  if (tid < 32) { int h = tid >> 3;
    float a = qpb[64 + tid]; const float* w = qpW + (64 + tid) * 32;
    for (int e = 0; e < 32; ++e) a += ctx4[h][e] * w[e]; o32[tid] = a; }
  __syncthreads();
  if (tid < 32) { float a = qpbo[tid]; const float* w = qpWo + tid * 32;
    for (int e = 0; e < 32; ++e) a += o32[e] * w[e]; t32[tid] = a; }
  __syncthreads();

  if (tid < 32) { float a = fb1[tid]; const float* w = fW1 + tid * 32;
    for (int e = 0; e < 32; ++e) a += t32[e] * w[e]; o32[tid] = fmaxf(a, 0.f); }
  __syncthreads();
  if (tid < 32) { float a = fb2[tid]; const float* w = fW2 + tid * 32;
    for (int e = 0; e < 32; ++e) a += o32[e] * w[e]; qbar[tid] = a; }
  __syncthreads();

  if (tid < 32) out[b * 32 + tid] = qbar[tid];
  if (tid == 0) {
    float g0 = gb[0], g1 = gb[1], g2 = gb[2];
    for (int e = 0; e < 32; ++e) { float f = qbar[e]; g0 += f * gW[e]; g1 += f * gW[32 + e]; g2 += f * gW[64 + e]; }
    float m = fmaxf(g0, fmaxf(g1, g2));
    float lse = m + logf(expf(g0 - m) + expf(g1 - m) + expf(g2 - m));
    float* og = out + 4096;
    og[b * 3 + 0] = g0 - lse; og[b * 3 + 1] = g1 - lse; og[b * 3 + 2] = g2 - lse;
    float hz = hb[0];
    for (int e = 0; e < 32; ++e) hz += qbar[e] * hW[e];
    out[4480 + b] = 1.f / (1.f + expf(-hz)) * 6.f - 3.f;
  }
}

extern "C" void kernel_launch(void* const* d_in, const int* in_sizes, int n_in,
                              void* d_out, int out_size, void* d_ws, size_t ws_size,
                              hipStream_t stream) {
  const float* x_omic = (const float*)d_in[0];
  const float* x_path = (const float*)d_in[1];
  const float* oW0 = (const float*)d_in[2];  const float* ob0 = (const float*)d_in[3];
  const float* oW1 = (const float*)d_in[4];  const float* ob1 = (const float*)d_in[5];
  const float* oW2 = (const float*)d_in[6];  const float* ob2 = (const float*)d_in[7];
  const float* oW3 = (const float*)d_in[8];  const float* ob3 = (const float*)d_in[9];
  const float* ln_g = (const float*)d_in[10]; const float* ln_b = (const float*)d_in[11];
  const float* cW  = (const float*)d_in[12]; const float* cb  = (const float*)d_in[13];
  const float* cWo = (const float*)d_in[14]; const float* cbo = (const float*)d_in[15];
  const float* qoW = (const float*)d_in[16]; const float* qob = (const float*)d_in[17];
  const float* qoWo = (const float*)d_in[18]; const float* qobo = (const float*)d_in[19];
  const float* qpW = (const float*)d_in[20]; const float* qpb = (const float*)d_in[21];
  const float* qpWo = (const float*)d_in[22]; const float* qpbo = (const float*)d_in[23];
  const float* fW1 = (const float*)d_in[24]; const float* fb1 = (const float*)d_in[25];
  const float* fW2 = (const float*)d_in[26]; const float* fb2 = (const float*)d_in[27];
  // d_in[28] = Qs — provably unused
  const float* gW = (const float*)d_in[29]; const float* gb = (const float*)d_in[30];
  const float* hW = (const float*)d_in[31]; const float* hb = (const float*)d_in[32];

  float* out = (float*)d_out;
  // workspace layout (24 MB total):
  ushort* qbf  = (ushort*)d_ws;          // 4 MB  bf16 [B,H,S,8] (scaled)
  ushort* kbf  = qbf + NQKV;             // 4 MB  bf16 [B,H,S,8]
  ushort* vtbf = kbf + NQKV;             // 4 MB  bf16 [B,H,8,S]
  ushort* obf  = vtbf + NQKV;            // 4 MB  bf16 [B,H,S,8]
  float*  img  = (float*)(obf + NQKV);   // 8 MB  fp32 [B,S,E]

  const int L = 11;  // layers 0..10 are dead code
  k_ln_qkv<<<8192, 256, 0, stream>>>(x_path, ln_g, ln_b, cW, cb, qbf, kbf, vtbf);
  k_attn<<<512, 512, 0, stream>>>(qbf, kbf, vtbf, obf);
  k_oproj<<<8192, 256, 0, stream>>>(obf, x_path, cWo, cbo, img);
  k_final<<<128, 256, 0, stream>>>(img, x_omic,
      oW0, ob0, oW1, ob1, oW2, ob2, oW3, ob3,
      qoW + L * 96 * 32, qob + L * 96, qoWo + L * 32 * 32, qobo + L * 32,
      qpW + L * 96 * 32, qpb + L * 96, qpWo + L * 32 * 32, qpbo + L * 32,
      fW1 + L * 32 * 32, fb1 + L * 32, fW2 + L * 32 * 32, fb2 + L * 32,
      gW, gb, hW, hb, out);
}

// Round 3
// 165.874 us; speedup vs baseline: 1.2727x; 1.1768x over previous
//
#include <hip/hip_runtime.h>
#include <hip/hip_bf16.h>

#define NQKV (128*4*512*8)   // 2,097,152 elements per q/k/v tensor

typedef __attribute__((ext_vector_type(8))) short short8;
typedef __attribute__((ext_vector_type(4))) float f32x4;

__device__ __forceinline__ float elu1(float x) { return x > 0.f ? x : expm1f(x); }
__device__ __forceinline__ unsigned pkbf(float a, float b) {
  return (unsigned)__bfloat16_as_ushort(__float2bfloat16(a)) |
         ((unsigned)__bfloat16_as_ushort(__float2bfloat16(b)) << 16);
}
__device__ __forceinline__ float bfu(unsigned u) { return __uint_as_float(u << 16); }

// ---------------------------------------------------------------------------
// K1: LayerNorm(x_path) -> QKV proj -> bf16 outputs.
//     q (pre-scaled by 1/sqrt(8)) and k in [B,H,S,8]; v transposed [B,H,8,S].
//     Block = 256 threads handles 8 consecutive rows s.
// ---------------------------------------------------------------------------
__global__ __launch_bounds__(256) void k_ln_qkv(
    const float* __restrict__ xp, const float* __restrict__ ln_g, const float* __restrict__ ln_b,
    const float* __restrict__ Wqkv, const float* __restrict__ bqkv,
    ushort* __restrict__ qbf, ushort* __restrict__ kbf, ushort* __restrict__ vtbf)
{
  __shared__ float WT[32][96];   // WT[e][c] = Wqkv[c][e]
  __shared__ float bsh[96];
  __shared__ float xn[8][32];
  __shared__ float qkv[8][96];
  int tid = threadIdx.x;
  for (int i = tid; i < 96 * 32; i += 256) WT[i & 31][i >> 5] = Wqkv[i];
  if (tid < 96) bsh[tid] = bqkv[tid];

  int g = tid >> 5, e = tid & 31;
  int row = blockIdx.x * 8 + g;
  float x = xp[row * 32 + e];
  float s1 = x, s2 = x * x;
  #pragma unroll
  for (int m = 16; m >= 1; m >>= 1) { s1 += __shfl_xor(s1, m, 32); s2 += __shfl_xor(s2, m, 32); }
  float mu  = s1 * 0.03125f;
  float var = s2 * 0.03125f - mu * mu;
  xn[g][e] = (x - mu) * rsqrtf(var + 1e-5f) * ln_g[e] + ln_b[e];
  __syncthreads();

  #pragma unroll
  for (int p = 0; p < 3; ++p) {
    int o = tid + p * 256;
    int r = o / 96, c = o - r * 96;
    float acc = bsh[c];
    const float* xr = xn[r];
    #pragma unroll
    for (int ee = 0; ee < 32; ++ee) acc += xr[ee] * WT[ee][c];
    qkv[r][c] = acc;
  }
  __syncthreads();

  // q/k: 256 threads -> 256 packed dword stores
  {
    const float sc = 0.35355339059327373f;  // fold 1/sqrt(8) into q
    int which = tid >> 7;           // 0: q, 1: k
    int r = (tid >> 4) & 7, h = (tid >> 2) & 3, pr = tid & 3;
    int cbase = which * 32 + h * 8 + pr * 2;
    float v0 = qkv[r][cbase], v1 = qkv[r][cbase + 1];
    if (which == 0) { v0 *= sc; v1 *= sc; }
    int s = blockIdx.x * 8 + r; int b = s >> 9; s &= 511;
    unsigned* dst = (unsigned*)(which ? kbf : qbf);
    dst[((b * 4 + h) * 512 + s) * 4 + pr] = pkbf(v0, v1);
  }
  // v^T: threads 0-31, one b128 each (8 consecutive s per channel)
  if (tid < 32) {
    int h = tid >> 3, d = tid & 7;
    float v[8];
    #pragma unroll
    for (int s8 = 0; s8 < 8; ++s8) v[s8] = qkv[s8][64 + tid];
    uint4 o4 = { pkbf(v[0], v[1]), pkbf(v[2], v[3]), pkbf(v[4], v[5]), pkbf(v[6], v[7]) };
    int s0 = blockIdx.x * 8; int b = s0 >> 9; int sl = s0 & 511;
    unsigned* dst = (unsigned*)vtbf + (((b * 4 + h) * 8 + d) * 512 + sl) / 2;
    *(uint4*)dst = o4;
  }
}

// ---------------------------------------------------------------------------
// K2: MFMA attention per (b,h).  Block = 512 threads (8 waves, 64 rows each).
//     S^T = K.Q^T via 16x16x32 bf16 (d=8 of K=32 used);
//     exp'd P -> per-wave-private LDS [16 qrow][128 kidx] bf16 with T2-style
//     XOR swizzle (byte ^= (qr&7)<<4) on BOTH write and read (rule #21);
//     O^T = V^T.P^T with full K=32, V-frags register-resident (NO spill:
//     launch_bounds(512,2) -> 256-VGPR cap; ~110 actual).
// ---------------------------------------------------------------------------
__global__ __launch_bounds__(512, 2) void k_attn(
    const ushort* __restrict__ qbf, const ushort* __restrict__ kbf,
    const ushort* __restrict__ vtbf, ushort* __restrict__ obf)
{
  __shared__ ushort ks[512 * 8];        // K  [s][d] bf16, 8KB
  __shared__ ushort vts[8 * 512];       // V^T [d][s] bf16, 8KB
  __shared__ ushort ps[8][16 * 128];    // per-wave P [16 qrow][128 kidx], swizzled, 32KB
  int tid = threadIdx.x;
  int bh = blockIdx.x;
  ((uint4*)ks)[tid]  = ((const uint4*)kbf)[bh * 512 + tid];
  ((uint4*)vts)[tid] = ((const uint4*)vtbf)[bh * 512 + tid];
  __syncthreads();

  int w = tid >> 6, lane = tid & 63, g = lane >> 4, qr = lane & 15;
  const short8 z8 = {0, 0, 0, 0, 0, 0, 0, 0};
  unsigned swz = (unsigned)(qr & 7) << 4;

  // V-frags: vf[i] lane holds V^T[d=qr (d<8), kidx=i*32 + g*8 + j]
  short8 vf[16];
  bool vact = qr < 8;
  #pragma unroll
  for (int i = 0; i < 16; ++i)
    vf[i] = vact ? *(const short8*)(vts + qr * 512 + i * 32 + g * 8) : z8;

  char* pwB = (char*)&ps[w][0] + qr * 256;

  for (int qg = 0; qg < 4; ++qg) {
    int q0 = w * 64 + qg * 16;
    // B-frag: Q^T -> lane holds Q[qrow=qr, d=j] for g==0; zeros else
    short8 qf = (g == 0) ? *(const short8*)(qbf + (bh * 512 + q0 + qr) * 8) : z8;
    f32x4 ot = {0.f, 0.f, 0.f, 0.f};
    float lp = 0.f;

    for (int c = 0; c < 4; ++c) {
      #pragma unroll
      for (int t = 0; t < 8; ++t) {
        int krow = c * 128 + t * 16;
        // A-frag: K rows -> lane holds K[krow+qr, d=j] for g==0; zeros else
        short8 af = (g == 0) ? *(const short8*)(ks + (krow + qr) * 8) : z8;
        f32x4 s4 = __builtin_amdgcn_mfma_f32_16x16x32_bf16(af, qf, (f32x4){0.f,0.f,0.f,0.f}, 0, 0, 0);
        // lane holds S^T[kidx_local = t*16 + g*4 + r, qrow = qr]
        float e0 = __expf(s4[0]), e1 = __expf(s4[1]);
        float e2 = __expf(s4[2]), e3 = __expf(s4[3]);
        lp += (e0 + e1) + (e2 + e3);
        uint2 pk2 = { pkbf(e0, e1), pkbf(e2, e3) };
        *(uint2*)(pwB + ((unsigned)((t * 16 + g * 4) << 1) ^ swz)) = pk2;
      }
      // PV for this 128-kidx chunk (K=32 per MFMA)
      #pragma unroll
      for (int tp = 0; tp < 4; ++tp) {
        short8 pb = *(const short8*)(pwB + ((unsigned)((tp * 32 + g * 8) << 1) ^ swz));
        ot = __builtin_amdgcn_mfma_f32_16x16x32_bf16(vf[c * 4 + tp], pb, ot, 0, 0, 0);
      }
    }
    // full row-sum for qrow=qr (partials live in 4 lane-groups)
    lp += __shfl_xor(lp, 16);
    lp += __shfl_xor(lp, 32);
    float rl = 1.f / lp;
    // O^T: lane holds O[qrow=qr, d=g*4+r], valid for g<2
    if (g < 2) {
      uint2 o2 = { pkbf(ot[0] * rl, ot[1] * rl), pkbf(ot[2] * rl, ot[3] * rl) };
      *(uint2*)((unsigned*)obf + (bh * 512 + q0 + qr) * 4 + g * 2) = o2;
    }
  }
}

// ---------------------------------------------------------------------------
// K3: out-projection + residual: img[b,s,:] = x_path[b,s,:] + o @ Wo^T + bo
//     o is bf16 in [B,H,S,8].
// ---------------------------------------------------------------------------
__global__ __launch_bounds__(256) void k_oproj(
    const ushort* __restrict__ obf, const float* __restrict__ xp,
    const float* __restrict__ Wo, const float* __restrict__ bo,
    float* __restrict__ img)
{
  __shared__ float WoT[32][32];  // WoT[e'][e] = Wo[e][e']
  __shared__ float bos[32];
  __shared__ float orow[8][32];
  int tid = threadIdx.x;
  for (int i = tid; i < 1024; i += 256) WoT[i & 31][i >> 5] = Wo[i];
  if (tid < 32) bos[tid] = bo[tid];
  if (tid < 64) {
    int r = tid >> 3, h = (tid >> 1) & 3, half = tid & 1;
    int s = blockIdx.x * 8 + r; int b = s >> 9; int sl = s & 511;
    uint2 u = *(const uint2*)((const unsigned*)obf + ((b * 4 + h) * 512 + sl) * 4 + half * 2);
    float* o4 = &orow[r][h * 8 + half * 4];
    o4[0] = bfu(u.x & 0xffffu); o4[1] = bfu(u.x >> 16);
    o4[2] = bfu(u.y & 0xffffu); o4[3] = bfu(u.y >> 16);
  }
  __syncthreads();

  int g = tid >> 5, e = tid & 31;
  int row = blockIdx.x * 8 + g;
  float acc = bos[e];
  const float* orr = orow[g];
  #pragma unroll
  for (int ee = 0; ee < 32; ++ee) acc += orr[ee] * WoT[ee][e];
  img[row * 32 + e] = xp[row * 32 + e] + acc;
}

// ---------------------------------------------------------------------------
// K4: everything else.  Layers 0..10 are dead code (qo-attention with a
//     single key ignores its query input).  Only layer 11 matters.
// ---------------------------------------------------------------------------
__global__ __launch_bounds__(256) void k_final(
    const float* __restrict__ img, const float* __restrict__ xo,
    const float* __restrict__ oW0, const float* __restrict__ ob0,
    const float* __restrict__ oW1, const float* __restrict__ ob1,
    const float* __restrict__ oW2, const float* __restrict__ ob2,
    const float* __restrict__ oW3, const float* __restrict__ ob3,
    const float* __restrict__ qoW, const float* __restrict__ qob,
    const float* __restrict__ qoWo, const float* __restrict__ qobo,
    const float* __restrict__ qpW, const float* __restrict__ qpb,
    const float* __restrict__ qpWo, const float* __restrict__ qpbo,
    const float* __restrict__ fW1, const float* __restrict__ fb1,
    const float* __restrict__ fW2, const float* __restrict__ fb2,
    const float* __restrict__ gW, const float* __restrict__ gb,
    const float* __restrict__ hW, const float* __restrict__ hb,
    float* __restrict__ out)
{
  __shared__ float p[4][512];
  __shared__ float partial[8][4][32];
  __shared__ float buf1[80], buf2[64];
  __shared__ float emb[32], qbar[32], qh[32], u[4][32], cc4[4], lsum[4], ctx4[4][32], t32[32], o32[32];
  int b = blockIdx.x, tid = threadIdx.x;

  if (tid < 80) buf1[tid] = xo[b * 80 + tid];
  __syncthreads();
  if (tid < 64) { float a = ob0[tid]; const float* w = oW0 + tid * 80;
    for (int e = 0; e < 80; ++e) a += buf1[e] * w[e]; buf2[tid] = elu1(a); }
  __syncthreads();
  if (tid < 48) { float a = ob1[tid]; const float* w = oW1 + tid * 64;
    for (int e = 0; e < 64; ++e) a += buf2[e] * w[e]; buf1[tid] = elu1(a); }
  __syncthreads();
  if (tid < 32) { float a = ob2[tid]; const float* w = oW2 + tid * 48;
    for (int e = 0; e < 48; ++e) a += buf1[e] * w[e]; buf2[tid] = elu1(a); }
  __syncthreads();
  if (tid < 32) { float a = ob3[tid]; const float* w = oW3 + tid * 32;
    for (int e = 0; e < 32; ++e) a += buf2[e] * w[e]; emb[tid] = elu1(a); }
  __syncthreads();

  if (tid < 32) { float a = qob[64 + tid]; const float* w = qoW + (64 + tid) * 32;
    for (int e = 0; e < 32; ++e) a += emb[e] * w[e]; t32[tid] = a; }
  __syncthreads();
  if (tid < 32) { float a = qobo[tid]; const float* w = qoWo + tid * 32;
    for (int e = 0; e < 32; ++e) a += t32[e] * w[e]; qbar[tid] = a; }
  __syncthreads();

  if (tid < 32) { float a = qpb[tid]; const float* w = qpW + tid * 32;
    for (int e = 0; e < 32; ++e) a += qbar[e] * w[e]; qh[tid] = a; }
  __syncthreads();
  if (tid < 128) {
    int h = tid >> 5, e = tid & 31;
    float a = 0.f;
    #pragma unroll
    for (int d = 0; d < 8; ++d) a += qh[h * 8 + d] * qpW[(32 + h * 8 + d) * 32 + e];
    u[h][e] = a;
    if (e == 0) { float c2 = 0.f; for (int d = 0; d < 8; ++d) c2 += qh[h * 8 + d] * qpb[32 + h * 8 + d]; cc4[h] = c2; }
  }
  __syncthreads();

  const float* ibase = img + b * 16384;
  #pragma unroll
  for (int j = 0; j < 8; ++j) {
    int idx = tid + j * 256; int h = idx >> 9, kk = idx & 511;
    const float4* ir = (const float4*)(ibase + kk * 32);
    const float* uh = u[h];
    float a = cc4[h];
    #pragma unroll
    for (int e4 = 0; e4 < 8; ++e4) {
      float4 t = ir[e4];
      a += uh[e4 * 4] * t.x + uh[e4 * 4 + 1] * t.y + uh[e4 * 4 + 2] * t.z + uh[e4 * 4 + 3] * t.w;
    }
    p[h][kk] = __expf(fminf(a * 0.35355339059327373f, 80.f));
  }
  __syncthreads();
  {
    int w = tid >> 6, lane = tid & 63;
    float a = 0.f;
    for (int kk = lane; kk < 512; kk += 64) a += p[w][kk];
    #pragma unroll
    for (int m = 32; m >= 1; m >>= 1) a += __shfl_xor(a, m, 64);
    if (lane == 0) lsum[w] = 1.f / a;
  }
  {
    int e = tid & 31, ch = tid >> 5;
    float a0 = 0.f, a1 = 0.f, a2 = 0.f, a3 = 0.f;
    for (int kk = ch * 64; kk < ch * 64 + 64; ++kk) {
      float val = ibase[kk * 32 + e];
      a0 += p[0][kk] * val; a1 += p[1][kk] * val; a2 += p[2][kk] * val; a3 += p[3][kk] * val;
    }
    partial[ch][0][e] = a0; partial[ch][1][e] = a1; partial[ch][2][e] = a2; partial[ch][3][e] = a3;
  }
  __syncthreads();
  if (tid < 128) {
    int h = tid >> 5, e = tid & 31;
    float a = 0.f;
    #pragma unroll
    for (int ch = 0; ch < 8; ++ch) a += partial[ch][h][e];
    ctx4[h][e] = a * lsum[h];
  }
  __syncthreads();
  if (tid < 32) { int h = tid >> 3;
    float a = qpb[64 + tid]; const float* w = qpW + (64 + tid) * 32;
    for (int e = 0; e < 32; ++e) a += ctx4[h][e] * w[e]; o32[tid] = a; }
  __syncthreads();
  if (tid < 32) { float a = qpbo[tid]; const float* w = qpWo + tid * 32;
    for (int e = 0; e < 32; ++e) a += o32[e] * w[e]; t32[tid] = a; }
  __syncthreads();

  if (tid < 32) { float a = fb1[tid]; const float* w = fW1 + tid * 32;
    for (int e = 0; e < 32; ++e) a += t32[e] * w[e]; o32[tid] = fmaxf(a, 0.f); }
  __syncthreads();
  if (tid < 32) { float a = fb2[tid]; const float* w = fW2 + tid * 32;
    for (int e = 0; e < 32; ++e) a += o32[e] * w[e]; qbar[tid] = a; }
  __syncthreads();

  if (tid < 32) out[b * 32 + tid] = qbar[tid];
  if (tid == 0) {
    float g0 = gb[0], g1 = gb[1], g2 = gb[2];
    for (int e = 0; e < 32; ++e) { float f = qbar[e]; g0 += f * gW[e]; g1 += f * gW[32 + e]; g2 += f * gW[64 + e]; }
    float m = fmaxf(g0, fmaxf(g1, g2));
    float lse = m + logf(expf(g0 - m) + expf(g1 - m) + expf(g2 - m));
    float* og = out + 4096;
    og[b * 3 + 0] = g0 - lse; og[b * 3 + 1] = g1 - lse; og[b * 3 + 2] = g2 - lse;
    float hz = hb[0];
    for (int e = 0; e < 32; ++e) hz += qbar[e] * hW[e];
    out[4480 + b] = 1.f / (1.f + expf(-hz)) * 6.f - 3.f;
  }
}

extern "C" void kernel_launch(void* const* d_in, const int* in_sizes, int n_in,
                              void* d_out, int out_size, void* d_ws, size_t ws_size,
                              hipStream_t stream) {
  const float* x_omic = (const float*)d_in[0];
  const float* x_path = (const float*)d_in[1];
  const float* oW0 = (const float*)d_in[2];  const float* ob0 = (const float*)d_in[3];
  const float* oW1 = (const float*)d_in[4];  const float* ob1 = (const float*)d_in[5];
  const float* oW2 = (const float*)d_in[6];  const float* ob2 = (const float*)d_in[7];
  const float* oW3 = (const float*)d_in[8];  const float* ob3 = (const float*)d_in[9];
  const float* ln_g = (const float*)d_in[10]; const float* ln_b = (const float*)d_in[11];
  const float* cW  = (const float*)d_in[12]; const float* cb  = (const float*)d_in[13];
  const float* cWo = (const float*)d_in[14]; const float* cbo = (const float*)d_in[15];
  const float* qoW = (const float*)d_in[16]; const float* qob = (const float*)d_in[17];
  const float* qoWo = (const float*)d_in[18]; const float* qobo = (const float*)d_in[19];
  const float* qpW = (const float*)d_in[20]; const float* qpb = (const float*)d_in[21];
  const float* qpWo = (const float*)d_in[22]; const float* qpbo = (const float*)d_in[23];
  const float* fW1 = (const float*)d_in[24]; const float* fb1 = (const float*)d_in[25];
  const float* fW2 = (const float*)d_in[26]; const float* fb2 = (const float*)d_in[27];
  // d_in[28] = Qs — provably unused
  const float* gW = (const float*)d_in[29]; const float* gb = (const float*)d_in[30];
  const float* hW = (const float*)d_in[31]; const float* hb = (const float*)d_in[32];

  float* out = (float*)d_out;
  // workspace layout (24 MB total):
  ushort* qbf  = (ushort*)d_ws;          // 4 MB  bf16 [B,H,S,8] (scaled)
  ushort* kbf  = qbf + NQKV;             // 4 MB  bf16 [B,H,S,8]
  ushort* vtbf = kbf + NQKV;             // 4 MB  bf16 [B,H,8,S]
  ushort* obf  = vtbf + NQKV;            // 4 MB  bf16 [B,H,S,8]
  float*  img  = (float*)(obf + NQKV);   // 8 MB  fp32 [B,S,E]

  const int L = 11;  // layers 0..10 are dead code
  k_ln_qkv<<<8192, 256, 0, stream>>>(x_path, ln_g, ln_b, cW, cb, qbf, kbf, vtbf);
  k_attn<<<512, 512, 0, stream>>>(qbf, kbf, vtbf, obf);
  k_oproj<<<8192, 256, 0, stream>>>(obf, x_path, cWo, cbo, img);
  k_final<<<128, 256, 0, stream>>>(img, x_omic,
      oW0, ob0, oW1, ob1, oW2, ob2, oW3, ob3,
      qoW + L * 96 * 32, qob + L * 96, qoWo + L * 32 * 32, qobo + L * 32,
      qpW + L * 96 * 32, qpb + L * 96, qpWo + L * 32 * 32, qpbo + L * 32,
      fW1 + L * 32 * 32, fb1 + L * 32, fW2 + L * 32 * 32, fb2 + L * 32,
      gW, gb, hW, hb, out);
}

// Round 4
// 127.998 us; speedup vs baseline: 1.6493x; 1.2959x over previous
//
#include <hip/hip_runtime.h>
#include <hip/hip_bf16.h>

#define NQKV (128*4*512*8)   // 2,097,152 elements per q/k/v tensor

typedef __attribute__((ext_vector_type(8))) short short8;
typedef __attribute__((ext_vector_type(4))) float f32x4;

__device__ __forceinline__ float elu1(float x) { return x > 0.f ? x : expm1f(x); }
__device__ __forceinline__ unsigned pkbf(float a, float b) {
  return (unsigned)__bfloat16_as_ushort(__float2bfloat16(a)) |
         ((unsigned)__bfloat16_as_ushort(__float2bfloat16(b)) << 16);
}
__device__ __forceinline__ float bfu(unsigned u) { return __uint_as_float(u << 16); }

// ---------------------------------------------------------------------------
// K1: LayerNorm(x_path) -> QKV proj -> bf16 outputs.
//     q (pre-scaled by 1/sqrt(8)) and k in [B,H,S,8]; v transposed [B,H,8,S].
//     1024 blocks x 256 threads; each block loads weights ONCE (LDS strides
//     padded odd -> all accesses <=2-way, free) and loops 8 row-groups of 8.
// ---------------------------------------------------------------------------
__global__ __launch_bounds__(256) void k_ln_qkv(
    const float* __restrict__ xp, const float* __restrict__ ln_g, const float* __restrict__ ln_b,
    const float* __restrict__ Wqkv, const float* __restrict__ bqkv,
    ushort* __restrict__ qbf, ushort* __restrict__ kbf, ushort* __restrict__ vtbf)
{
  __shared__ float WT[32][97];   // WT[e][c] = Wqkv[c][e]; stride 97: store banks (lane+c)%32
  __shared__ float bsh[96];
  __shared__ float xn[8][33];
  __shared__ float qkv[8][97];
  int tid = threadIdx.x;
  for (int i = tid; i < 96 * 32; i += 256) WT[i & 31][i >> 5] = Wqkv[i];
  if (tid < 96) bsh[tid] = bqkv[tid];
  float lg = ln_g[tid & 31], lb = ln_b[tid & 31];
  __syncthreads();

  int g = tid >> 5, e = tid & 31;

  for (int it = 0; it < 8; ++it) {
    int row = blockIdx.x * 64 + it * 8 + g;
    float x = xp[row * 32 + e];
    float s1 = x, s2 = x * x;
    #pragma unroll
    for (int m = 16; m >= 1; m >>= 1) { s1 += __shfl_xor(s1, m, 32); s2 += __shfl_xor(s2, m, 32); }
    float mu  = s1 * 0.03125f;
    float var = s2 * 0.03125f - mu * mu;
    xn[g][e] = (x - mu) * rsqrtf(var + 1e-5f) * lg + lb;
    __syncthreads();

    #pragma unroll
    for (int p = 0; p < 3; ++p) {
      int o = tid + p * 256;
      int r = o / 96, c = o - r * 96;
      float acc = bsh[c];
      const float* xr = xn[r];
      #pragma unroll
      for (int ee = 0; ee < 32; ++ee) acc += xr[ee] * WT[ee][c];
      qkv[r][c] = acc;
    }
    __syncthreads();

    // q/k: 256 threads -> 256 packed dword stores
    {
      const float sc = 0.35355339059327373f;  // fold 1/sqrt(8) into q
      int which = tid >> 7;           // 0: q, 1: k
      int r = (tid >> 4) & 7, h = (tid >> 2) & 3, pr = tid & 3;
      int cbase = which * 32 + h * 8 + pr * 2;
      float v0 = qkv[r][cbase], v1 = qkv[r][cbase + 1];
      if (which == 0) { v0 *= sc; v1 *= sc; }
      int s = blockIdx.x * 64 + it * 8 + r; int b = s >> 9; s &= 511;
      unsigned* dst = (unsigned*)(which ? kbf : qbf);
      dst[((b * 4 + h) * 512 + s) * 4 + pr] = pkbf(v0, v1);
    }
    // v^T: threads 0-31, one uint4 each (8 consecutive s per channel)
    if (tid < 32) {
      float v[8];
      #pragma unroll
      for (int s8 = 0; s8 < 8; ++s8) v[s8] = qkv[s8][64 + tid];
      uint4 o4 = { pkbf(v[0], v[1]), pkbf(v[2], v[3]), pkbf(v[4], v[5]), pkbf(v[6], v[7]) };
      int h = tid >> 3, d = tid & 7;
      int s0 = blockIdx.x * 64 + it * 8; int b = s0 >> 9; int sl = s0 & 511;
      unsigned* dst = (unsigned*)vtbf + (((b * 4 + h) * 8 + d) * 512 + sl) / 2;
      *(uint4*)dst = o4;
    }
    // next iteration's post-LN barrier separates this pack phase from the
    // next projection's qkv overwrite (2 barriers per iteration total)
  }
}

// ---------------------------------------------------------------------------
// K2: MFMA attention per (b,h).  Block = 512 threads (8 waves, 64 rows each).
//     S^T = K.Q^T via 16x16x32 bf16 (d=8 of K=32 used);
//     exp'd P -> per-wave-private LDS [16 qrow][128 kidx] bf16 with XOR
//     swizzle (byte ^= (qr&7)<<4) on BOTH write and read;
//     O^T = V^T.P^T with full K=32, V-frags register-resident.
// ---------------------------------------------------------------------------
__global__ __launch_bounds__(512, 2) void k_attn(
    const ushort* __restrict__ qbf, const ushort* __restrict__ kbf,
    const ushort* __restrict__ vtbf, ushort* __restrict__ obf)
{
  __shared__ ushort ks[512 * 8];        // K  [s][d] bf16, 8KB
  __shared__ ushort vts[8 * 512];       // V^T [d][s] bf16, 8KB
  __shared__ ushort ps[8][16 * 128];    // per-wave P [16 qrow][128 kidx], swizzled, 32KB
  int tid = threadIdx.x;
  int bh = blockIdx.x;
  ((uint4*)ks)[tid]  = ((const uint4*)kbf)[bh * 512 + tid];
  ((uint4*)vts)[tid] = ((const uint4*)vtbf)[bh * 512 + tid];
  __syncthreads();

  int w = tid >> 6, lane = tid & 63, g = lane >> 4, qr = lane & 15;
  const short8 z8 = {0, 0, 0, 0, 0, 0, 0, 0};
  unsigned swz = (unsigned)(qr & 7) << 4;

  // V-frags: vf[i] lane holds V^T[d=qr (d<8), kidx=i*32 + g*8 + j]
  short8 vf[16];
  bool vact = qr < 8;
  #pragma unroll
  for (int i = 0; i < 16; ++i)
    vf[i] = vact ? *(const short8*)(vts + qr * 512 + i * 32 + g * 8) : z8;

  char* pwB = (char*)&ps[w][0] + qr * 256;

  for (int qg = 0; qg < 4; ++qg) {
    int q0 = w * 64 + qg * 16;
    // B-frag: Q^T -> lane holds Q[qrow=qr, d=j] for g==0; zeros else
    short8 qf = (g == 0) ? *(const short8*)(qbf + (bh * 512 + q0 + qr) * 8) : z8;
    f32x4 ot = {0.f, 0.f, 0.f, 0.f};
    float lp = 0.f;

    for (int c = 0; c < 4; ++c) {
      #pragma unroll
      for (int t = 0; t < 8; ++t) {
        int krow = c * 128 + t * 16;
        // A-frag: K rows -> lane holds K[krow+qr, d=j] for g==0; zeros else
        short8 af = (g == 0) ? *(const short8*)(ks + (krow + qr) * 8) : z8;
        f32x4 s4 = __builtin_amdgcn_mfma_f32_16x16x32_bf16(af, qf, (f32x4){0.f,0.f,0.f,0.f}, 0, 0, 0);
        // lane holds S^T[kidx_local = t*16 + g*4 + r, qrow = qr]
        float e0 = __expf(s4[0]), e1 = __expf(s4[1]);
        float e2 = __expf(s4[2]), e3 = __expf(s4[3]);
        lp += (e0 + e1) + (e2 + e3);
        uint2 pk2 = { pkbf(e0, e1), pkbf(e2, e3) };
        *(uint2*)(pwB + ((unsigned)((t * 16 + g * 4) << 1) ^ swz)) = pk2;
      }
      // PV for this 128-kidx chunk (K=32 per MFMA)
      #pragma unroll
      for (int tp = 0; tp < 4; ++tp) {
        short8 pb = *(const short8*)(pwB + ((unsigned)((tp * 32 + g * 8) << 1) ^ swz));
        ot = __builtin_amdgcn_mfma_f32_16x16x32_bf16(vf[c * 4 + tp], pb, ot, 0, 0, 0);
      }
    }
    // full row-sum for qrow=qr (partials live in 4 lane-groups)
    lp += __shfl_xor(lp, 16);
    lp += __shfl_xor(lp, 32);
    float rl = 1.f / lp;
    // O^T: lane holds O[qrow=qr, d=g*4+r], valid for g<2
    if (g < 2) {
      uint2 o2 = { pkbf(ot[0] * rl, ot[1] * rl), pkbf(ot[2] * rl, ot[3] * rl) };
      *(uint2*)((unsigned*)obf + (bh * 512 + q0 + qr) * 4 + g * 2) = o2;
    }
  }
}

// ---------------------------------------------------------------------------
// K3: out-projection + residual: img[b,s,:] = x_path[b,s,:] + o @ Wo^T + bo
//     o is bf16 in [B,H,S,8].  1024 blocks; weights loaded once; 8 iters.
// ---------------------------------------------------------------------------
__global__ __launch_bounds__(256) void k_oproj(
    const ushort* __restrict__ obf, const float* __restrict__ xp,
    const float* __restrict__ Wo, const float* __restrict__ bo,
    float* __restrict__ img)
{
  __shared__ float WoT[32][33];  // WoT[e'][e] = Wo[e][e']; stride 33 -> conflict-free
  __shared__ float bos[32];
  __shared__ float orow[8][33];
  int tid = threadIdx.x;
  for (int i = tid; i < 1024; i += 256) WoT[i & 31][i >> 5] = Wo[i];
  if (tid < 32) bos[tid] = bo[tid];
  __syncthreads();

  int g = tid >> 5, e = tid & 31;

  for (int it = 0; it < 8; ++it) {
    if (tid < 64) {
      int r = tid >> 3, h = (tid >> 1) & 3, half = tid & 1;
      int s = blockIdx.x * 64 + it * 8 + r; int b = s >> 9; int sl = s & 511;
      uint2 u = *(const uint2*)((const unsigned*)obf + ((b * 4 + h) * 512 + sl) * 4 + half * 2);
      float* o4 = &orow[r][h * 8 + half * 4];
      o4[0] = bfu(u.x & 0xffffu); o4[1] = bfu(u.x >> 16);
      o4[2] = bfu(u.y & 0xffffu); o4[3] = bfu(u.y >> 16);
    }
    __syncthreads();

    int row = blockIdx.x * 64 + it * 8 + g;
    float acc = bos[e];
    const float* orr = orow[g];
    #pragma unroll
    for (int ee = 0; ee < 32; ++ee) acc += orr[ee] * WoT[ee][e];
    img[row * 32 + e] = xp[row * 32 + e] + acc;
    __syncthreads();   // protect orow before next iteration's overwrite
  }
}

// ---------------------------------------------------------------------------
// K4: everything else.  Layers 0..10 are dead code (qo-attention with a
//     single key ignores its query input).  Only layer 11 matters.
// ---------------------------------------------------------------------------
__global__ __launch_bounds__(256) void k_final(
    const float* __restrict__ img, const float* __restrict__ xo,
    const float* __restrict__ oW0, const float* __restrict__ ob0,
    const float* __restrict__ oW1, const float* __restrict__ ob1,
    const float* __restrict__ oW2, const float* __restrict__ ob2,
    const float* __restrict__ oW3, const float* __restrict__ ob3,
    const float* __restrict__ qoW, const float* __restrict__ qob,
    const float* __restrict__ qoWo, const float* __restrict__ qobo,
    const float* __restrict__ qpW, const float* __restrict__ qpb,
    const float* __restrict__ qpWo, const float* __restrict__ qpbo,
    const float* __restrict__ fW1, const float* __restrict__ fb1,
    const float* __restrict__ fW2, const float* __restrict__ fb2,
    const float* __restrict__ gW, const float* __restrict__ gb,
    const float* __restrict__ hW, const float* __restrict__ hb,
    float* __restrict__ out)
{
  __shared__ float p[4][512];
  __shared__ float partial[8][4][32];
  __shared__ float buf1[80], buf2[64];
  __shared__ float emb[32], qbar[32], qh[32], u[4][32], cc4[4], lsum[4], ctx4[4][32], t32[32], o32[32];
  int b = blockIdx.x, tid = threadIdx.x;

  if (tid < 80) buf1[tid] = xo[b * 80 + tid];
  __syncthreads();
  if (tid < 64) { float a = ob0[tid]; const float* w = oW0 + tid * 80;
    for (int e = 0; e < 80; ++e) a += buf1[e] * w[e]; buf2[tid] = elu1(a); }
  __syncthreads();
  if (tid < 48) { float a = ob1[tid]; const float* w = oW1 + tid * 64;
    for (int e = 0; e < 64; ++e) a += buf2[e] * w[e]; buf1[tid] = elu1(a); }
  __syncthreads();
  if (tid < 32) { float a = ob2[tid]; const float* w = oW2 + tid * 48;
    for (int e = 0; e < 48; ++e) a += buf1[e] * w[e]; buf2[tid] = elu1(a); }
  __syncthreads();
  if (tid < 32) { float a = ob3[tid]; const float* w = oW3 + tid * 32;
    for (int e = 0; e < 32; ++e) a += buf2[e] * w[e]; emb[tid] = elu1(a); }
  __syncthreads();

  if (tid < 32) { float a = qob[64 + tid]; const float* w = qoW + (64 + tid) * 32;
    for (int e = 0; e < 32; ++e) a += emb[e] * w[e]; t32[tid] = a; }
  __syncthreads();
  if (tid < 32) { float a = qobo[tid]; const float* w = qoWo + tid * 32;
    for (int e = 0; e < 32; ++e) a += t32[e] * w[e]; qbar[tid] = a; }
  __syncthreads();

  if (tid < 32) { float a = qpb[tid]; const float* w = qpW + tid * 32;
    for (int e = 0; e < 32; ++e) a += qbar[e] * w[e]; qh[tid] = a; }
  __syncthreads();
  if (tid < 128) {
    int h = tid >> 5, e = tid & 31;
    float a = 0.f;
    #pragma unroll
    for (int d = 0; d < 8; ++d) a += qh[h * 8 + d] * qpW[(32 + h * 8 + d) * 32 + e];
    u[h][e] = a;
    if (e == 0) { float c2 = 0.f; for (int d = 0; d < 8; ++d) c2 += qh[h * 8 + d] * qpb[32 + h * 8 + d]; cc4[h] = c2; }
  }
  __syncthreads();

  const float* ibase = img + b * 16384;
  #pragma unroll
  for (int j = 0; j < 8; ++j) {
    int idx = tid + j * 256; int h = idx >> 9, kk = idx & 511;
    const float4* ir = (const float4*)(ibase + kk * 32);
    const float* uh = u[h];
    float a = cc4[h];
    #pragma unroll
    for (int e4 = 0; e4 < 8; ++e4) {
      float4 t = ir[e4];
      a += uh[e4 * 4] * t.x + uh[e4 * 4 + 1] * t.y + uh[e4 * 4 + 2] * t.z + uh[e4 * 4 + 3] * t.w;
    }
    p[h][kk] = __expf(fminf(a * 0.35355339059327373f, 80.f));
  }
  __syncthreads();
  {
    int w = tid >> 6, lane = tid & 63;
    float a = 0.f;
    for (int kk = lane; kk < 512; kk += 64) a += p[w][kk];
    #pragma unroll
    for (int m = 32; m >= 1; m >>= 1) a += __shfl_xor(a, m, 64);
    if (lane == 0) lsum[w] = 1.f / a;
  }
  {
    int e = tid & 31, ch = tid >> 5;
    float a0 = 0.f, a1 = 0.f, a2 = 0.f, a3 = 0.f;
    for (int kk = ch * 64; kk < ch * 64 + 64; ++kk) {
      float val = ibase[kk * 32 + e];
      a0 += p[0][kk] * val; a1 += p[1][kk] * val; a2 += p[2][kk] * val; a3 += p[3][kk] * val;
    }
    partial[ch][0][e] = a0; partial[ch][1][e] = a1; partial[ch][2][e] = a2; partial[ch][3][e] = a3;
  }
  __syncthreads();
  if (tid < 128) {
    int h = tid >> 5, e = tid & 31;
    float a = 0.f;
    #pragma unroll
    for (int ch = 0; ch < 8; ++ch) a += partial[ch][h][e];
    ctx4[h][e] = a * lsum[h];
  }
  __syncthreads();
  if (tid < 32) { int h = tid >> 3;
    float a = qpb[64 + tid]; const float* w = qpW + (64 + tid) * 32;
    for (int e = 0; e < 32; ++e) a += ctx4[h][e] * w[e]; o32[tid] = a; }
  __syncthreads();
  if (tid < 32) { float a = qpbo[tid]; const float* w = qpWo + tid * 32;
    for (int e = 0; e < 32; ++e) a += o32[e] * w[e]; t32[tid] = a; }
  __syncthreads();

  if (tid < 32) { float a = fb1[tid]; const float* w = fW1 + tid * 32;
    for (int e = 0; e < 32; ++e) a += t32[e] * w[e]; o32[tid] = fmaxf(a, 0.f); }
  __syncthreads();
  if (tid < 32) { float a = fb2[tid]; const float* w = fW2 + tid * 32;
    for (int e = 0; e < 32; ++e) a += o32[e] * w[e]; qbar[tid] = a; }
  __syncthreads();

  if (tid < 32) out[b * 32 + tid] = qbar[tid];
  if (tid == 0) {
    float g0 = gb[0], g1 = gb[1], g2 = gb[2];
    for (int e = 0; e < 32; ++e) { float f = qbar[e]; g0 += f * gW[e]; g1 += f * gW[32 + e]; g2 += f * gW[64 + e]; }
    float m = fmaxf(g0, fmaxf(g1, g2));
    float lse = m + logf(expf(g0 - m) + expf(g1 - m) + expf(g2 - m));
    float* og = out + 4096;
    og[b * 3 + 0] = g0 - lse; og[b * 3 + 1] = g1 - lse; og[b * 3 + 2] = g2 - lse;
    float hz = hb[0];
    for (int e = 0; e < 32; ++e) hz += qbar[e] * hW[e];
    out[4480 + b] = 1.f / (1.f + expf(-hz)) * 6.f - 3.f;
  }
}

extern "C" void kernel_launch(void* const* d_in, const int* in_sizes, int n_in,
                              void* d_out, int out_size, void* d_ws, size_t ws_size,
                              hipStream_t stream) {
  const float* x_omic = (const float*)d_in[0];
  const float* x_path = (const float*)d_in[1];
  const float* oW0 = (const float*)d_in[2];  const float* ob0 = (const float*)d_in[3];
  const float* oW1 = (const float*)d_in[4];  const float* ob1 = (const float*)d_in[5];
  const float* oW2 = (const float*)d_in[6];  const float* ob2 = (const float*)d_in[7];
  const float* oW3 = (const float*)d_in[8];  const float* ob3 = (const float*)d_in[9];
  const float* ln_g = (const float*)d_in[10]; const float* ln_b = (const float*)d_in[11];
  const float* cW  = (const float*)d_in[12]; const float* cb  = (const float*)d_in[13];
  const float* cWo = (const float*)d_in[14]; const float* cbo = (const float*)d_in[15];
  const float* qoW = (const float*)d_in[16]; const float* qob = (const float*)d_in[17];
  const float* qoWo = (const float*)d_in[18]; const float* qobo = (const float*)d_in[19];
  const float* qpW = (const float*)d_in[20]; const float* qpb = (const float*)d_in[21];
  const float* qpWo = (const float*)d_in[22]; const float* qpbo = (const float*)d_in[23];
  const float* fW1 = (const float*)d_in[24]; const float* fb1 = (const float*)d_in[25];
  const float* fW2 = (const float*)d_in[26]; const float* fb2 = (const float*)d_in[27];
  // d_in[28] = Qs — provably unused
  const float* gW = (const float*)d_in[29]; const float* gb = (const float*)d_in[30];
  const float* hW = (const float*)d_in[31]; const float* hb = (const float*)d_in[32];

  float* out = (float*)d_out;
  // workspace layout (24 MB total):
  ushort* qbf  = (ushort*)d_ws;          // 4 MB  bf16 [B,H,S,8] (scaled)
  ushort* kbf  = qbf + NQKV;             // 4 MB  bf16 [B,H,S,8]
  ushort* vtbf = kbf + NQKV;             // 4 MB  bf16 [B,H,8,S]
  ushort* obf  = vtbf + NQKV;            // 4 MB  bf16 [B,H,S,8]
  float*  img  = (float*)(obf + NQKV);   // 8 MB  fp32 [B,S,E]

  const int L = 11;  // layers 0..10 are dead code
  k_ln_qkv<<<1024, 256, 0, stream>>>(x_path, ln_g, ln_b, cW, cb, qbf, kbf, vtbf);
  k_attn<<<512, 512, 0, stream>>>(qbf, kbf, vtbf, obf);
  k_oproj<<<1024, 256, 0, stream>>>(obf, x_path, cWo, cbo, img);
  k_final<<<128, 256, 0, stream>>>(img, x_omic,
      oW0, ob0, oW1, ob1, oW2, ob2, oW3, ob3,
      qoW + L * 96 * 32, qob + L * 96, qoWo + L * 32 * 32, qobo + L * 32,
      qpW + L * 96 * 32, qpb + L * 96, qpWo + L * 32 * 32, qpbo + L * 32,
      fW1 + L * 32 * 32, fb1 + L * 32, fW2 + L * 32 * 32, fb2 + L * 32,
      gW, gb, hW, hb, out);
}

// Round 5
// 121.625 us; speedup vs baseline: 1.7357x; 1.0524x over previous
//
#include <hip/hip_runtime.h>
#include <hip/hip_bf16.h>

#define NQKV (128*4*512*8)   // 2,097,152 elements per q/k/v tensor

typedef __attribute__((ext_vector_type(8))) short short8;
typedef __attribute__((ext_vector_type(4))) float f32x4;

__device__ __forceinline__ float elu1(float x) { return x > 0.f ? x : expm1f(x); }
__device__ __forceinline__ unsigned pkbf(float a, float b) {
  return (unsigned)__bfloat16_as_ushort(__float2bfloat16(a)) |
         ((unsigned)__bfloat16_as_ushort(__float2bfloat16(b)) << 16);
}
// truncation pack (a -> low16, b -> high16); bias cancels in softmax ratio
__device__ __forceinline__ unsigned pk_trunc(float a, float b) {
  return (__float_as_uint(a) >> 16) | (__float_as_uint(b) & 0xffff0000u);
}
__device__ __forceinline__ float bfu(unsigned u) { return __uint_as_float(u << 16); }

// ---------------------------------------------------------------------------
// K1: LayerNorm(x_path) -> QKV proj -> bf16 outputs.
//     q pre-scaled by log2(e)/sqrt(8) (consumed by exp2-based softmax);
//     k in [B,H,S,8]; v transposed [B,H,8,S].
//     1024 blocks x 256 threads; weights loaded once; 8 row-groups of 8.
// ---------------------------------------------------------------------------
__global__ __launch_bounds__(256) void k_ln_qkv(
    const float* __restrict__ xp, const float* __restrict__ ln_g, const float* __restrict__ ln_b,
    const float* __restrict__ Wqkv, const float* __restrict__ bqkv,
    ushort* __restrict__ qbf, ushort* __restrict__ kbf, ushort* __restrict__ vtbf)
{
  __shared__ float WT[32][97];   // WT[e][c] = Wqkv[c][e]
  __shared__ float bsh[96];
  __shared__ float xn[8][33];
  __shared__ float qkv[8][97];
  int tid = threadIdx.x;
  for (int i = tid; i < 96 * 32; i += 256) WT[i & 31][i >> 5] = Wqkv[i];
  if (tid < 96) bsh[tid] = bqkv[tid];
  float lg = ln_g[tid & 31], lb = ln_b[tid & 31];
  __syncthreads();

  int g = tid >> 5, e = tid & 31;

  for (int it = 0; it < 8; ++it) {
    int row = blockIdx.x * 64 + it * 8 + g;
    float x = xp[row * 32 + e];
    float s1 = x, s2 = x * x;
    #pragma unroll
    for (int m = 16; m >= 1; m >>= 1) { s1 += __shfl_xor(s1, m, 32); s2 += __shfl_xor(s2, m, 32); }
    float mu  = s1 * 0.03125f;
    float var = s2 * 0.03125f - mu * mu;
    xn[g][e] = (x - mu) * rsqrtf(var + 1e-5f) * lg + lb;
    __syncthreads();

    #pragma unroll
    for (int p = 0; p < 3; ++p) {
      int o = tid + p * 256;
      int r = o / 96, c = o - r * 96;
      float acc = bsh[c];
      const float* xr = xn[r];
      #pragma unroll
      for (int ee = 0; ee < 32; ++ee) acc += xr[ee] * WT[ee][c];
      qkv[r][c] = acc;
    }
    __syncthreads();

    {
      const float sc = 0.35355339059327373f * 1.4426950408889634f;  // 1/sqrt(8) * log2(e)
      int which = tid >> 7;           // 0: q, 1: k
      int r = (tid >> 4) & 7, h = (tid >> 2) & 3, pr = tid & 3;
      int cbase = which * 32 + h * 8 + pr * 2;
      float v0 = qkv[r][cbase], v1 = qkv[r][cbase + 1];
      if (which == 0) { v0 *= sc; v1 *= sc; }
      int s = blockIdx.x * 64 + it * 8 + r; int b = s >> 9; s &= 511;
      unsigned* dst = (unsigned*)(which ? kbf : qbf);
      dst[((b * 4 + h) * 512 + s) * 4 + pr] = pkbf(v0, v1);
    }
    if (tid < 32) {
      float v[8];
      #pragma unroll
      for (int s8 = 0; s8 < 8; ++s8) v[s8] = qkv[s8][64 + tid];
      uint4 o4 = { pkbf(v[0], v[1]), pkbf(v[2], v[3]), pkbf(v[4], v[5]), pkbf(v[6], v[7]) };
      int h = tid >> 3, d = tid & 7;
      int s0 = blockIdx.x * 64 + it * 8; int b = s0 >> 9; int sl = s0 & 511;
      unsigned* dst = (unsigned*)vtbf + (((b * 4 + h) * 8 + d) * 512 + sl) / 2;
      *(uint4*)dst = o4;
    }
  }
}

// ---------------------------------------------------------------------------
// K2: MFMA attention.  Grid = 512 bh x 2 q-halves; block = 512 thr (8 waves),
//     each wave owns 2 q-groups of 16 rows.  c-outer loop over 8 chunks of
//     64 kidx: QK^T (16x16x32, d=8 of K), exp2, trunc-pack -> swizzled
//     per-wave P LDS; PV with V-frags from LDS per chunk.  Row-sum comes
//     FREE from the PV MFMA: V^T A-row d=8 is set to bf16 1.0, so output
//     row 8 = sum_k P[k][q] (numerator & denominator share truncated P).
// ---------------------------------------------------------------------------
__global__ __launch_bounds__(512, 6) void k_attn(
    const ushort* __restrict__ qbf, const ushort* __restrict__ kbf,
    const ushort* __restrict__ vtbf, ushort* __restrict__ obf)
{
  __shared__ ushort ks[512 * 8];        // K  [s][d] bf16, 8KB
  __shared__ ushort vts[8 * 512];       // V^T [d][s] bf16, 8KB
  __shared__ ushort ps[8][16 * 64];     // per-wave P [16 qrow][64 kidx], swizzled, 16KB
  int tid = threadIdx.x;
  int bh = blockIdx.x >> 1, qhalf = blockIdx.x & 1;
  ((uint4*)ks)[tid]  = ((const uint4*)kbf)[bh * 512 + tid];
  ((uint4*)vts)[tid] = ((const uint4*)vtbf)[bh * 512 + tid];
  __syncthreads();

  int w = tid >> 6, lane = tid & 63, g = lane >> 4, qr = lane & 15;
  const short8 z8 = {0, 0, 0, 0, 0, 0, 0, 0};
  const short8 one8 = {(short)0x3F80, (short)0x3F80, (short)0x3F80, (short)0x3F80,
                       (short)0x3F80, (short)0x3F80, (short)0x3F80, (short)0x3F80};
  unsigned swz = (unsigned)(qr & 7) << 4;
  char* pwB = (char*)&ps[w][0] + qr * 128;

  int qbase = qhalf * 256 + w * 32;
  const short8* qrow0 = (const short8*)(qbf + (bh * 512 + qbase + qr) * 8);
  short8 qf0 = (g == 0) ? qrow0[0] : z8;
  short8 qf1 = (g == 0) ? qrow0[2] : z8;   // +16 rows = +2 short8
  f32x4 ot0 = {0.f, 0.f, 0.f, 0.f}, ot1 = {0.f, 0.f, 0.f, 0.f};

  for (int c = 0; c < 8; ++c) {
    short8 vf0, vf1;
    {
      const short8* vp = (const short8*)(vts + qr * 512 + c * 64 + g * 8);
      vf0 = (qr < 8) ? vp[0] : (qr == 8 ? one8 : z8);
      vf1 = (qr < 8) ? vp[4] : (qr == 8 ? one8 : z8);   // +32 kidx = +4 short8
    }
    #pragma unroll
    for (int qg = 0; qg < 2; ++qg) {
      short8 qf = qg ? qf1 : qf0;
      #pragma unroll
      for (int t = 0; t < 4; ++t) {
        short8 af = (g == 0) ? *(const short8*)(ks + (c * 64 + t * 16 + qr) * 8) : z8;
        f32x4 s4 = __builtin_amdgcn_mfma_f32_16x16x32_bf16(af, qf, (f32x4){0.f,0.f,0.f,0.f}, 0, 0, 0);
        // lane holds S^T[kidx_local = t*16 + g*4 + r, qrow = qr]
        float e0 = exp2f(s4[0]), e1 = exp2f(s4[1]);
        float e2 = exp2f(s4[2]), e3 = exp2f(s4[3]);
        uint2 pk2 = { pk_trunc(e0, e1), pk_trunc(e2, e3) };
        *(uint2*)(pwB + ((unsigned)((t * 16 + g * 4) << 1) ^ swz)) = pk2;
      }
      #pragma unroll
      for (int tp = 0; tp < 2; ++tp) {
        short8 pb = *(const short8*)(pwB + ((unsigned)((tp * 32 + g * 8) << 1) ^ swz));
        f32x4& ot = qg ? ot1 : ot0;
        ot = __builtin_amdgcn_mfma_f32_16x16x32_bf16(tp ? vf1 : vf0, pb, ot, 0, 0, 0);
      }
    }
  }

  // normalize + store: row-sum for qrow=qr sits in lane (g=2,qr) reg 0 (d=8)
  #pragma unroll
  for (int qg = 0; qg < 2; ++qg) {
    f32x4 ot = qg ? ot1 : ot0;
    float lpv = __shfl(ot[0], 32 + qr, 64);
    float rl = 1.f / lpv;
    if (g < 2) {
      int rowg = bh * 512 + qbase + qg * 16 + qr;
      uint2 o2 = { pkbf(ot[0] * rl, ot[1] * rl), pkbf(ot[2] * rl, ot[3] * rl) };
      *(uint2*)((unsigned*)obf + rowg * 4 + g * 2) = o2;
    }
  }
}

// ---------------------------------------------------------------------------
// K3: out-projection + residual: img[b,s,:] = x_path[b,s,:] + o @ Wo^T + bo
//     o is bf16 in [B,H,S,8].  1024 blocks; weights loaded once; 8 iters.
// ---------------------------------------------------------------------------
__global__ __launch_bounds__(256) void k_oproj(
    const ushort* __restrict__ obf, const float* __restrict__ xp,
    const float* __restrict__ Wo, const float* __restrict__ bo,
    float* __restrict__ img)
{
  __shared__ float WoT[32][33];
  __shared__ float bos[32];
  __shared__ float orow[8][33];
  int tid = threadIdx.x;
  for (int i = tid; i < 1024; i += 256) WoT[i & 31][i >> 5] = Wo[i];
  if (tid < 32) bos[tid] = bo[tid];
  __syncthreads();

  int g = tid >> 5, e = tid & 31;

  for (int it = 0; it < 8; ++it) {
    if (tid < 64) {
      int r = tid >> 3, h = (tid >> 1) & 3, half = tid & 1;
      int s = blockIdx.x * 64 + it * 8 + r; int b = s >> 9; int sl = s & 511;
      uint2 u = *(const uint2*)((const unsigned*)obf + ((b * 4 + h) * 512 + sl) * 4 + half * 2);
      float* o4 = &orow[r][h * 8 + half * 4];
      o4[0] = bfu(u.x & 0xffffu); o4[1] = bfu(u.x >> 16);
      o4[2] = bfu(u.y & 0xffffu); o4[3] = bfu(u.y >> 16);
    }
    __syncthreads();

    int row = blockIdx.x * 64 + it * 8 + g;
    float acc = bos[e];
    const float* orr = orow[g];
    #pragma unroll
    for (int ee = 0; ee < 32; ++ee) acc += orr[ee] * WoT[ee][e];
    img[row * 32 + e] = xp[row * 32 + e] + acc;
    __syncthreads();
  }
}

// ---------------------------------------------------------------------------
// K4: everything else.  Layers 0..10 are dead code (qo-attention with a
//     single key ignores its query input).  Only layer 11 matters.
// ---------------------------------------------------------------------------
__global__ __launch_bounds__(256) void k_final(
    const float* __restrict__ img, const float* __restrict__ xo,
    const float* __restrict__ oW0, const float* __restrict__ ob0,
    const float* __restrict__ oW1, const float* __restrict__ ob1,
    const float* __restrict__ oW2, const float* __restrict__ ob2,
    const float* __restrict__ oW3, const float* __restrict__ ob3,
    const float* __restrict__ qoW, const float* __restrict__ qob,
    const float* __restrict__ qoWo, const float* __restrict__ qobo,
    const float* __restrict__ qpW, const float* __restrict__ qpb,
    const float* __restrict__ qpWo, const float* __restrict__ qpbo,
    const float* __restrict__ fW1, const float* __restrict__ fb1,
    const float* __restrict__ fW2, const float* __restrict__ fb2,
    const float* __restrict__ gW, const float* __restrict__ gb,
    const float* __restrict__ hW, const float* __restrict__ hb,
    float* __restrict__ out)
{
  __shared__ float p[4][512];
  __shared__ float partial[8][4][32];
  __shared__ float buf1[80], buf2[64];
  __shared__ float emb[32], qbar[32], qh[32], u[4][32], cc4[4], lsum[4], ctx4[4][32], t32[32], o32[32];
  int b = blockIdx.x, tid = threadIdx.x;

  if (tid < 80) buf1[tid] = xo[b * 80 + tid];
  __syncthreads();
  if (tid < 64) { float a = ob0[tid]; const float* w = oW0 + tid * 80;
    for (int e = 0; e < 80; ++e) a += buf1[e] * w[e]; buf2[tid] = elu1(a); }
  __syncthreads();
  if (tid < 48) { float a = ob1[tid]; const float* w = oW1 + tid * 64;
    for (int e = 0; e < 64; ++e) a += buf2[e] * w[e]; buf1[tid] = elu1(a); }
  __syncthreads();
  if (tid < 32) { float a = ob2[tid]; const float* w = oW2 + tid * 48;
    for (int e = 0; e < 48; ++e) a += buf1[e] * w[e]; buf2[tid] = elu1(a); }
  __syncthreads();
  if (tid < 32) { float a = ob3[tid]; const float* w = oW3 + tid * 32;
    for (int e = 0; e < 32; ++e) a += buf2[e] * w[e]; emb[tid] = elu1(a); }
  __syncthreads();

  if (tid < 32) { float a = qob[64 + tid]; const float* w = qoW + (64 + tid) * 32;
    for (int e = 0; e < 32; ++e) a += emb[e] * w[e]; t32[tid] = a; }
  __syncthreads();
  if (tid < 32) { float a = qobo[tid]; const float* w = qoWo + tid * 32;
    for (int e = 0; e < 32; ++e) a += t32[e] * w[e]; qbar[tid] = a; }
  __syncthreads();

  if (tid < 32) { float a = qpb[tid]; const float* w = qpW + tid * 32;
    for (int e = 0; e < 32; ++e) a += qbar[e] * w[e]; qh[tid] = a; }
  __syncthreads();
  if (tid < 128) {
    int h = tid >> 5, e = tid & 31;
    float a = 0.f;
    #pragma unroll
    for (int d = 0; d < 8; ++d) a += qh[h * 8 + d] * qpW[(32 + h * 8 + d) * 32 + e];
    u[h][e] = a;
    if (e == 0) { float c2 = 0.f; for (int d = 0; d < 8; ++d) c2 += qh[h * 8 + d] * qpb[32 + h * 8 + d]; cc4[h] = c2; }
  }
  __syncthreads();

  const float* ibase = img + b * 16384;
  #pragma unroll
  for (int j = 0; j < 8; ++j) {
    int idx = tid + j * 256; int h = idx >> 9, kk = idx & 511;
    const float4* ir = (const float4*)(ibase + kk * 32);
    const float* uh = u[h];
    float a = cc4[h];
    #pragma unroll
    for (int e4 = 0; e4 < 8; ++e4) {
      float4 t = ir[e4];
      a += uh[e4 * 4] * t.x + uh[e4 * 4 + 1] * t.y + uh[e4 * 4 + 2] * t.z + uh[e4 * 4 + 3] * t.w;
    }
    // exp(a/sqrt(8)) = exp2(a * log2(e)/sqrt(8))
    p[h][kk] = exp2f(fminf(a * 0.51006979f, 115.f));
  }
  __syncthreads();
  {
    int w = tid >> 6, lane = tid & 63;
    float a = 0.f;
    for (int kk = lane; kk < 512; kk += 64) a += p[w][kk];
    #pragma unroll
    for (int m = 32; m >= 1; m >>= 1) a += __shfl_xor(a, m, 64);
    if (lane == 0) lsum[w] = 1.f / a;
  }
  {
    int e = tid & 31, ch = tid >> 5;
    float a0 = 0.f, a1 = 0.f, a2 = 0.f, a3 = 0.f;
    for (int kk = ch * 64; kk < ch * 64 + 64; ++kk) {
      float val = ibase[kk * 32 + e];
      a0 += p[0][kk] * val; a1 += p[1][kk] * val; a2 += p[2][kk] * val; a3 += p[3][kk] * val;
    }
    partial[ch][0][e] = a0; partial[ch][1][e] = a1; partial[ch][2][e] = a2; partial[ch][3][e] = a3;
  }
  __syncthreads();
  if (tid < 128) {
    int h = tid >> 5, e = tid & 31;
    float a = 0.f;
    #pragma unroll
    for (int ch = 0; ch < 8; ++ch) a += partial[ch][h][e];
    ctx4[h][e] = a * lsum[h];
  }
  __syncthreads();
  if (tid < 32) { int h = tid >> 3;
    float a = qpb[64 + tid]; const float* w = qpW + (64 + tid) * 32;
    for (int e = 0; e < 32; ++e) a += ctx4[h][e] * w[e]; o32[tid] = a; }
  __syncthreads();
  if (tid < 32) { float a = qpbo[tid]; const float* w = qpWo + tid * 32;
    for (int e = 0; e < 32; ++e) a += o32[e] * w[e]; t32[tid] = a; }
  __syncthreads();

  if (tid < 32) { float a = fb1[tid]; const float* w = fW1 + tid * 32;
    for (int e = 0; e < 32; ++e) a += t32[e] * w[e]; o32[tid] = fmaxf(a, 0.f); }
  __syncthreads();
  if (tid < 32) { float a = fb2[tid]; const float* w = fW2 + tid * 32;
    for (int e = 0; e < 32; ++e) a += o32[e] * w[e]; qbar[tid] = a; }
  __syncthreads();

  if (tid < 32) out[b * 32 + tid] = qbar[tid];
  if (tid == 0) {
    float g0 = gb[0], g1 = gb[1], g2 = gb[2];
    for (int e = 0; e < 32; ++e) { float f = qbar[e]; g0 += f * gW[e]; g1 += f * gW[32 + e]; g2 += f * gW[64 + e]; }
    float m = fmaxf(g0, fmaxf(g1, g2));
    float lse = m + logf(expf(g0 - m) + expf(g1 - m) + expf(g2 - m));
    float* og = out + 4096;
    og[b * 3 + 0] = g0 - lse; og[b * 3 + 1] = g1 - lse; og[b * 3 + 2] = g2 - lse;
    float hz = hb[0];
    for (int e = 0; e < 32; ++e) hz += qbar[e] * hW[e];
    out[4480 + b] = 1.f / (1.f + expf(-hz)) * 6.f - 3.f;
  }
}

extern "C" void kernel_launch(void* const* d_in, const int* in_sizes, int n_in,
                              void* d_out, int out_size, void* d_ws, size_t ws_size,
                              hipStream_t stream) {
  const float* x_omic = (const float*)d_in[0];
  const float* x_path = (const float*)d_in[1];
  const float* oW0 = (const float*)d_in[2];  const float* ob0 = (const float*)d_in[3];
  const float* oW1 = (const float*)d_in[4];  const float* ob1 = (const float*)d_in[5];
  const float* oW2 = (const float*)d_in[6];  const float* ob2 = (const float*)d_in[7];
  const float* oW3 = (const float*)d_in[8];  const float* ob3 = (const float*)d_in[9];
  const float* ln_g = (const float*)d_in[10]; const float* ln_b = (const float*)d_in[11];
  const float* cW  = (const float*)d_in[12]; const float* cb  = (const float*)d_in[13];
  const float* cWo = (const float*)d_in[14]; const float* cbo = (const float*)d_in[15];
  const float* qoW = (const float*)d_in[16]; const float* qob = (const float*)d_in[17];
  const float* qoWo = (const float*)d_in[18]; const float* qobo = (const float*)d_in[19];
  const float* qpW = (const float*)d_in[20]; const float* qpb = (const float*)d_in[21];
  const float* qpWo = (const float*)d_in[22]; const float* qpbo = (const float*)d_in[23];
  const float* fW1 = (const float*)d_in[24]; const float* fb1 = (const float*)d_in[25];
  const float* fW2 = (const float*)d_in[26]; const float* fb2 = (const float*)d_in[27];
  // d_in[28] = Qs — provably unused
  const float* gW = (const float*)d_in[29]; const float* gb = (const float*)d_in[30];
  const float* hW = (const float*)d_in[31]; const float* hb = (const float*)d_in[32];

  float* out = (float*)d_out;
  ushort* qbf  = (ushort*)d_ws;          // 4 MB  bf16 [B,H,S,8] (scaled by log2e/sqrt8)
  ushort* kbf  = qbf + NQKV;             // 4 MB  bf16 [B,H,S,8]
  ushort* vtbf = kbf + NQKV;             // 4 MB  bf16 [B,H,8,S]
  ushort* obf  = vtbf + NQKV;            // 4 MB  bf16 [B,H,S,8]
  float*  img  = (float*)(obf + NQKV);   // 8 MB  fp32 [B,S,E]

  const int L = 11;  // layers 0..10 are dead code
  k_ln_qkv<<<1024, 256, 0, stream>>>(x_path, ln_g, ln_b, cW, cb, qbf, kbf, vtbf);
  k_attn<<<1024, 512, 0, stream>>>(qbf, kbf, vtbf, obf);
  k_oproj<<<1024, 256, 0, stream>>>(obf, x_path, cWo, cbo, img);
  k_final<<<128, 256, 0, stream>>>(img, x_omic,
      oW0, ob0, oW1, ob1, oW2, ob2, oW3, ob3,
      qoW + L * 96 * 32, qob + L * 96, qoWo + L * 32 * 32, qobo + L * 32,
      qpW + L * 96 * 32, qpb + L * 96, qpWo + L * 32 * 32, qpbo + L * 32,
      fW1 + L * 32 * 32, fb1 + L * 32, fW2 + L * 32 * 32, fb2 + L * 32,
      gW, gb, hW, hb, out);
}

// Round 6
// 73.360 us; speedup vs baseline: 2.8777x; 1.6579x over previous
//
#include <hip/hip_runtime.h>
#include <hip/hip_bf16.h>

#define NQKV (128*4*512*8)   // 2,097,152 elements per q/k/v tensor

typedef __attribute__((ext_vector_type(8))) short short8;
typedef __attribute__((ext_vector_type(4))) float f32x4;

__device__ __forceinline__ float elu1(float x) { return x > 0.f ? x : expm1f(x); }
__device__ __forceinline__ unsigned pkbf(float a, float b) {
  return (unsigned)__bfloat16_as_ushort(__float2bfloat16(a)) |
         ((unsigned)__bfloat16_as_ushort(__float2bfloat16(b)) << 16);
}
// truncation pack (a -> low16, b -> high16); bias cancels in softmax ratio
__device__ __forceinline__ unsigned pk_trunc(float a, float b) {
  return (__float_as_uint(a) >> 16) | (__float_as_uint(b) & 0xffff0000u);
}
__device__ __forceinline__ float bfu(unsigned u) { return __uint_as_float(u << 16); }
__device__ __forceinline__ short8 cvt8(float4 a, float4 b, float s) {
  uint4 u = { pkbf(a.x * s, a.y * s), pkbf(a.z * s, a.w * s),
              pkbf(b.x * s, b.y * s), pkbf(b.z * s, b.w * s) };
  union { uint4 u4; short8 s8; } c; c.u4 = u; return c.s8;
}

// ---------------------------------------------------------------------------
// K1: LayerNorm(x_path) -> QKV proj, MFMA-based, LDS-free, barrier-free.
//     Computes QKV^T = W . xn^T per 16-row chunk: A = W rows (K=32 full),
//     B = xn (lane (g,qr) holds xn[s=qr][e=g*8..+7] -- exactly what its own
//     LN pass produced), C-init = bias.  q tiles pre-scaled by log2e/sqrt8.
//     Outputs: q,k bf16 [B,H,S,8]; v^T bf16 [B,H,8,S].
//     Grid 1024 x 256 (4 waves); wave = one 16-row chunk.
// ---------------------------------------------------------------------------
__global__ __launch_bounds__(256) void k_ln_qkv(
    const float* __restrict__ xp, const float* __restrict__ ln_g, const float* __restrict__ ln_b,
    const float* __restrict__ Wqkv, const float* __restrict__ bqkv,
    ushort* __restrict__ qbf, ushort* __restrict__ kbf, ushort* __restrict__ vtbf)
{
  const float sc = 0.35355339059327373f * 1.4426950408889634f;  // 1/sqrt(8)*log2(e)
  int tid = threadIdx.x, w = tid >> 6, lane = tid & 63;
  int g = lane >> 4, qr = lane & 15;

  // A-frags: 6 tiles (q:0-1, k:2-3, v:4-5); lane holds W[c=t*16+qr][e=g*8+j]
  short8 wa[6];
  f32x4 bc[6];
  #pragma unroll
  for (int t = 0; t < 6; ++t) {
    const float4* wr = (const float4*)(Wqkv + (t * 16 + qr) * 32 + g * 8);
    float s = (t < 2) ? sc : 1.f;
    wa[t] = cvt8(wr[0], wr[1], s);
    const float4 bb = *(const float4*)(bqkv + t * 16 + g * 4);
    bc[t] = (f32x4){bb.x * s, bb.y * s, bb.z * s, bb.w * s};
  }

  int row = blockIdx.x * 64 + w * 16 + qr;       // global s-row this lane owns
  int b = row >> 9, sl = row & 511;

  // LN: lane loads xn[row][g*8..+7]; row-sum via shfl_xor(16),(32)
  const float4* xr = (const float4*)(xp + row * 32 + g * 8);
  float4 x0 = xr[0], x1 = xr[1];
  float s1 = x0.x + x0.y + x0.z + x0.w + x1.x + x1.y + x1.z + x1.w;
  float s2 = x0.x*x0.x + x0.y*x0.y + x0.z*x0.z + x0.w*x0.w
           + x1.x*x1.x + x1.y*x1.y + x1.z*x1.z + x1.w*x1.w;
  s1 += __shfl_xor(s1, 16); s1 += __shfl_xor(s1, 32);
  s2 += __shfl_xor(s2, 16); s2 += __shfl_xor(s2, 32);
  float mu = s1 * 0.03125f;
  float rs = rsqrtf(s2 * 0.03125f - mu * mu + 1e-5f);
  const float4* lg4 = (const float4*)(ln_g + g * 8);
  const float4* lb4 = (const float4*)(ln_b + g * 8);
  float4 ga = lg4[0], gb2 = lg4[1], ba = lb4[0], bb2 = lb4[1];
  float4 n0 = { (x0.x-mu)*rs*ga.x+ba.x, (x0.y-mu)*rs*ga.y+ba.y,
                (x0.z-mu)*rs*ga.z+ba.z, (x0.w-mu)*rs*ga.w+ba.w };
  float4 n1 = { (x1.x-mu)*rs*gb2.x+bb2.x, (x1.y-mu)*rs*gb2.y+bb2.y,
                (x1.z-mu)*rs*gb2.z+bb2.z, (x1.w-mu)*rs*gb2.w+bb2.w };
  short8 bx = cvt8(n0, n1, 1.f);   // B-frag: xn[s=qr][e=g*8+j]

  // 6 MFMAs; lane then holds QKV^T[c=t*16+g*4+r][s=qr]
  #pragma unroll
  for (int t = 0; t < 6; ++t) {
    f32x4 ct = __builtin_amdgcn_mfma_f32_16x16x32_bf16(wa[t], bx, bc[t], 0, 0, 0);
    if (t < 4) {
      int c0 = (t & 1) * 16 + g * 4;          // col within q or k block
      int h = c0 >> 3, d0 = c0 & 7;
      unsigned* dst = (unsigned*)(t < 2 ? qbf : kbf);
      uint2 o2 = { pkbf(ct[0], ct[1]), pkbf(ct[2], ct[3]) };
      *(uint2*)(dst + ((b * 4 + h) * 512 + sl) * 4 + (d0 >> 1)) = o2;
    } else {
      int vc0 = (t - 4) * 16 + g * 4;
      int h = vc0 >> 3, d0 = vc0 & 7;
      #pragma unroll
      for (int r = 0; r < 4; ++r)
        vtbf[((b * 4 + h) * 8 + d0 + r) * 512 + sl] =
            __bfloat16_as_ushort(__float2bfloat16(ct[r]));
    }
  }
}

// ---------------------------------------------------------------------------
// K2: MFMA attention.  Grid = 512 bh x 2 q-halves; block = 512 thr (8 waves),
//     wave owns 2 q-groups of 16 rows.  Per 64-kidx chunk: K-frag loaded ONCE
//     and shared by both q-groups (dual per-wave P buffers); exp via raw
//     v_exp_f32; trunc-pack; PV row-sum free via ones-row d=8 of V^T.
// ---------------------------------------------------------------------------
__global__ __launch_bounds__(512, 4) void k_attn(
    const ushort* __restrict__ qbf, const ushort* __restrict__ kbf,
    const ushort* __restrict__ vtbf, ushort* __restrict__ obf)
{
  __shared__ ushort ks[512 * 8];          // K  [s][d] bf16, 8KB
  __shared__ ushort vts[8 * 512];         // V^T [d][s] bf16, 8KB
  __shared__ ushort ps[8][2][16 * 64];    // per-wave, per-qg P, swizzled, 32KB
  int tid = threadIdx.x;
  int bh = blockIdx.x >> 1, qhalf = blockIdx.x & 1;
  ((uint4*)ks)[tid]  = ((const uint4*)kbf)[bh * 512 + tid];
  ((uint4*)vts)[tid] = ((const uint4*)vtbf)[bh * 512 + tid];
  __syncthreads();

  int w = tid >> 6, lane = tid & 63, g = lane >> 4, qr = lane & 15;
  const short8 z8 = {0, 0, 0, 0, 0, 0, 0, 0};
  const short8 one8 = {(short)0x3F80, (short)0x3F80, (short)0x3F80, (short)0x3F80,
                       (short)0x3F80, (short)0x3F80, (short)0x3F80, (short)0x3F80};
  unsigned swz = (unsigned)(qr & 7) << 4;
  char* p0 = (char*)&ps[w][0][0] + qr * 128;
  char* p1 = (char*)&ps[w][1][0] + qr * 128;

  int qbase = qhalf * 256 + w * 32;
  const short8* qrow = (const short8*)(qbf + (bh * 512 + qbase + qr) * 8);
  short8 qf0 = (g == 0) ? qrow[0]  : z8;
  short8 qf1 = (g == 0) ? qrow[16] : z8;   // +16 rows (bugfix: was [2])
  f32x4 ot0 = {0.f, 0.f, 0.f, 0.f}, ot1 = {0.f, 0.f, 0.f, 0.f};

  for (int c = 0; c < 8; ++c) {
    const short8* vp = (const short8*)(vts + qr * 512 + c * 64 + g * 8);
    short8 vf0 = (qr < 8) ? vp[0] : (qr == 8 ? one8 : z8);
    short8 vf1 = (qr < 8) ? vp[4] : (qr == 8 ? one8 : z8);
    #pragma unroll
    for (int t = 0; t < 4; ++t) {
      short8 af = (g == 0) ? *(const short8*)(ks + (c * 64 + t * 16 + qr) * 8) : z8;
      f32x4 sa = __builtin_amdgcn_mfma_f32_16x16x32_bf16(af, qf0, (f32x4){0.f,0.f,0.f,0.f}, 0, 0, 0);
      f32x4 sb = __builtin_amdgcn_mfma_f32_16x16x32_bf16(af, qf1, (f32x4){0.f,0.f,0.f,0.f}, 0, 0, 0);
      unsigned off = (unsigned)((t * 16 + g * 4) << 1) ^ swz;
      uint2 pa = { pk_trunc(__builtin_amdgcn_exp2f(sa[0]), __builtin_amdgcn_exp2f(sa[1])),
                   pk_trunc(__builtin_amdgcn_exp2f(sa[2]), __builtin_amdgcn_exp2f(sa[3])) };
      uint2 pb2 = { pk_trunc(__builtin_amdgcn_exp2f(sb[0]), __builtin_amdgcn_exp2f(sb[1])),
                    pk_trunc(__builtin_amdgcn_exp2f(sb[2]), __builtin_amdgcn_exp2f(sb[3])) };
      *(uint2*)(p0 + off) = pa;
      *(uint2*)(p1 + off) = pb2;
    }
    #pragma unroll
    for (int tp = 0; tp < 2; ++tp) {
      unsigned off = (unsigned)((tp * 32 + g * 8) << 1) ^ swz;
      short8 vv = tp ? vf1 : vf0;
      short8 pba = *(const short8*)(p0 + off);
      short8 pbb = *(const short8*)(p1 + off);
      ot0 = __builtin_amdgcn_mfma_f32_16x16x32_bf16(vv, pba, ot0, 0, 0, 0);
      ot1 = __builtin_amdgcn_mfma_f32_16x16x32_bf16(vv, pbb, ot1, 0, 0, 0);
    }
  }

  // normalize + store: row-sum for qrow=qr sits in lane (g=2,qr) reg 0 (d=8)
  #pragma unroll
  for (int qg = 0; qg < 2; ++qg) {
    f32x4 ot = qg ? ot1 : ot0;
    float lpv = __shfl(ot[0], 32 + qr, 64);
    float rl = 1.f / lpv;
    if (g < 2) {
      int rowg = bh * 512 + qbase + qg * 16 + qr;
      uint2 o2 = { pkbf(ot[0] * rl, ot[1] * rl), pkbf(ot[2] * rl, ot[3] * rl) };
      *(uint2*)((unsigned*)obf + rowg * 4 + g * 2) = o2;
    }
  }
}

// ---------------------------------------------------------------------------
// K3: out-projection + residual, MFMA-based, LDS-free, barrier-free.
//     img^T[e][s] = Wo . O^T + bo;  B-frag for lane (g,qr) is obf head g of
//     row s=qr (one global b128).  Epilogue adds x_path, stores img float4.
//     Grid 1024 x 256; wave = one 16-row chunk.
// ---------------------------------------------------------------------------
__global__ __launch_bounds__(256) void k_oproj(
    const ushort* __restrict__ obf, const float* __restrict__ xp,
    const float* __restrict__ Wo, const float* __restrict__ bo,
    float* __restrict__ img)
{
  int tid = threadIdx.x, w = tid >> 6, lane = tid & 63;
  int g = lane >> 4, qr = lane & 15;

  short8 wa[2]; f32x4 bc[2];
  #pragma unroll
  for (int t = 0; t < 2; ++t) {
    const float4* wr = (const float4*)(Wo + (t * 16 + qr) * 32 + g * 8);
    wa[t] = cvt8(wr[0], wr[1], 1.f);
    const float4 bb = *(const float4*)(bo + t * 16 + g * 4);
    bc[t] = (f32x4){bb.x, bb.y, bb.z, bb.w};
  }

  int row = blockIdx.x * 64 + w * 16 + qr;
  int b = row >> 9, sl = row & 511;
  short8 ob = *(const short8*)(obf + ((b * 4 + g) * 512 + sl) * 8);

  #pragma unroll
  for (int t = 0; t < 2; ++t) {
    f32x4 ct = __builtin_amdgcn_mfma_f32_16x16x32_bf16(wa[t], ob, bc[t], 0, 0, 0);
    int e0 = t * 16 + g * 4;
    float4 xv = *(const float4*)(xp + row * 32 + e0);
    float4 o4 = { xv.x + ct[0], xv.y + ct[1], xv.z + ct[2], xv.w + ct[3] };
    *(float4*)(img + row * 32 + e0) = o4;
  }
}

// ---------------------------------------------------------------------------
// K4: everything else.  Layers 0..10 are dead code (qo-attention with a
//     single key ignores its query input).  Only layer 11 matters.
// ---------------------------------------------------------------------------
__global__ __launch_bounds__(256) void k_final(
    const float* __restrict__ img, const float* __restrict__ xo,
    const float* __restrict__ oW0, const float* __restrict__ ob0,
    const float* __restrict__ oW1, const float* __restrict__ ob1,
    const float* __restrict__ oW2, const float* __restrict__ ob2,
    const float* __restrict__ oW3, const float* __restrict__ ob3,
    const float* __restrict__ qoW, const float* __restrict__ qob,
    const float* __restrict__ qoWo, const float* __restrict__ qobo,
    const float* __restrict__ qpW, const float* __restrict__ qpb,
    const float* __restrict__ qpWo, const float* __restrict__ qpbo,
    const float* __restrict__ fW1, const float* __restrict__ fb1,
    const float* __restrict__ fW2, const float* __restrict__ fb2,
    const float* __restrict__ gW, const float* __restrict__ gb,
    const float* __restrict__ hW, const float* __restrict__ hb,
    float* __restrict__ out)
{
  __shared__ float p[4][512];
  __shared__ float partial[8][4][32];
  __shared__ float buf1[80], buf2[64];
  __shared__ float emb[32], qbar[32], qh[32], u[4][32], cc4[4], lsum[4], ctx4[4][32], t32[32], o32[32];
  int b = blockIdx.x, tid = threadIdx.x;

  if (tid < 80) buf1[tid] = xo[b * 80 + tid];
  __syncthreads();
  if (tid < 64) { float a = ob0[tid]; const float* w = oW0 + tid * 80;
    for (int e = 0; e < 80; ++e) a += buf1[e] * w[e]; buf2[tid] = elu1(a); }
  __syncthreads();
  if (tid < 48) { float a = ob1[tid]; const float* w = oW1 + tid * 64;
    for (int e = 0; e < 64; ++e) a += buf2[e] * w[e]; buf1[tid] = elu1(a); }
  __syncthreads();
  if (tid < 32) { float a = ob2[tid]; const float* w = oW2 + tid * 48;
    for (int e = 0; e < 48; ++e) a += buf1[e] * w[e]; buf2[tid] = elu1(a); }
  __syncthreads();
  if (tid < 32) { float a = ob3[tid]; const float* w = oW3 + tid * 32;
    for (int e = 0; e < 32; ++e) a += buf2[e] * w[e]; emb[tid] = elu1(a); }
  __syncthreads();

  if (tid < 32) { float a = qob[64 + tid]; const float* w = qoW + (64 + tid) * 32;
    for (int e = 0; e < 32; ++e) a += emb[e] * w[e]; t32[tid] = a; }
  __syncthreads();
  if (tid < 32) { float a = qobo[tid]; const float* w = qoWo + tid * 32;
    for (int e = 0; e < 32; ++e) a += t32[e] * w[e]; qbar[tid] = a; }
  __syncthreads();

  if (tid < 32) { float a = qpb[tid]; const float* w = qpW + tid * 32;
    for (int e = 0; e < 32; ++e) a += qbar[e] * w[e]; qh[tid] = a; }
  __syncthreads();
  if (tid < 128) {
    int h = tid >> 5, e = tid & 31;
    float a = 0.f;
    #pragma unroll
    for (int d = 0; d < 8; ++d) a += qh[h * 8 + d] * qpW[(32 + h * 8 + d) * 32 + e];
    u[h][e] = a;
    if (e == 0) { float c2 = 0.f; for (int d = 0; d < 8; ++d) c2 += qh[h * 8 + d] * qpb[32 + h * 8 + d]; cc4[h] = c2; }
  }
  __syncthreads();

  const float* ibase = img + b * 16384;
  #pragma unroll
  for (int j = 0; j < 8; ++j) {
    int idx = tid + j * 256; int h = idx >> 9, kk = idx & 511;
    const float4* ir = (const float4*)(ibase + kk * 32);
    const float* uh = u[h];
    float a = cc4[h];
    #pragma unroll
    for (int e4 = 0; e4 < 8; ++e4) {
      float4 t = ir[e4];
      a += uh[e4 * 4] * t.x + uh[e4 * 4 + 1] * t.y + uh[e4 * 4 + 2] * t.z + uh[e4 * 4 + 3] * t.w;
    }
    p[h][kk] = __builtin_amdgcn_exp2f(fminf(a * 0.51006979f, 115.f));
  }
  __syncthreads();
  {
    int w = tid >> 6, lane = tid & 63;
    float a = 0.f;
    for (int kk = lane; kk < 512; kk += 64) a += p[w][kk];
    #pragma unroll
    for (int m = 32; m >= 1; m >>= 1) a += __shfl_xor(a, m, 64);
    if (lane == 0) lsum[w] = 1.f / a;
  }
  {
    int e = tid & 31, ch = tid >> 5;
    float a0 = 0.f, a1 = 0.f, a2 = 0.f, a3 = 0.f;
    for (int kk = ch * 64; kk < ch * 64 + 64; ++kk) {
      float val = ibase[kk * 32 + e];
      a0 += p[0][kk] * val; a1 += p[1][kk] * val; a2 += p[2][kk] * val; a3 += p[3][kk] * val;
    }
    partial[ch][0][e] = a0; partial[ch][1][e] = a1; partial[ch][2][e] = a2; partial[ch][3][e] = a3;
  }
  __syncthreads();
  if (tid < 128) {
    int h = tid >> 5, e = tid & 31;
    float a = 0.f;
    #pragma unroll
    for (int ch = 0; ch < 8; ++ch) a += partial[ch][h][e];
    ctx4[h][e] = a * lsum[h];
  }
  __syncthreads();
  if (tid < 32) { int h = tid >> 3;
    float a = qpb[64 + tid]; const float* w = qpW + (64 + tid) * 32;
    for (int e = 0; e < 32; ++e) a += ctx4[h][e] * w[e]; o32[tid] = a; }
  __syncthreads();
  if (tid < 32) { float a = qpbo[tid]; const float* w = qpWo + tid * 32;
    for (int e = 0; e < 32; ++e) a += o32[e] * w[e]; t32[tid] = a; }
  __syncthreads();

  if (tid < 32) { float a = fb1[tid]; const float* w = fW1 + tid * 32;
    for (int e = 0; e < 32; ++e) a += t32[e] * w[e]; o32[tid] = fmaxf(a, 0.f); }
  __syncthreads();
  if (tid < 32) { float a = fb2[tid]; const float* w = fW2 + tid * 32;
    for (int e = 0; e < 32; ++e) a += o32[e] * w[e]; qbar[tid] = a; }
  __syncthreads();

  if (tid < 32) out[b * 32 + tid] = qbar[tid];
  if (tid == 0) {
    float g0 = gb[0], g1 = gb[1], g2 = gb[2];
    for (int e = 0; e < 32; ++e) { float f = qbar[e]; g0 += f * gW[e]; g1 += f * gW[32 + e]; g2 += f * gW[64 + e]; }
    float m = fmaxf(g0, fmaxf(g1, g2));
    float lse = m + logf(expf(g0 - m) + expf(g1 - m) + expf(g2 - m));
    float* og = out + 4096;
    og[b * 3 + 0] = g0 - lse; og[b * 3 + 1] = g1 - lse; og[b * 3 + 2] = g2 - lse;
    float hz = hb[0];
    for (int e = 0; e < 32; ++e) hz += qbar[e] * hW[e];
    out[4480 + b] = 1.f / (1.f + expf(-hz)) * 6.f - 3.f;
  }
}

extern "C" void kernel_launch(void* const* d_in, const int* in_sizes, int n_in,
                              void* d_out, int out_size, void* d_ws, size_t ws_size,
                              hipStream_t stream) {
  const float* x_omic = (const float*)d_in[0];
  const float* x_path = (const float*)d_in[1];
  const float* oW0 = (const float*)d_in[2];  const float* ob0 = (const float*)d_in[3];
  const float* oW1 = (const float*)d_in[4];  const float* ob1 = (const float*)d_in[5];
  const float* oW2 = (const float*)d_in[6];  const float* ob2 = (const float*)d_in[7];
  const float* oW3 = (const float*)d_in[8];  const float* ob3 = (const float*)d_in[9];
  const float* ln_g = (const float*)d_in[10]; const float* ln_b = (const float*)d_in[11];
  const float* cW  = (const float*)d_in[12]; const float* cb  = (const float*)d_in[13];
  const float* cWo = (const float*)d_in[14]; const float* cbo = (const float*)d_in[15];
  const float* qoW = (const float*)d_in[16]; const float* qob = (const float*)d_in[17];
  const float* qoWo = (const float*)d_in[18]; const float* qobo = (const float*)d_in[19];
  const float* qpW = (const float*)d_in[20]; const float* qpb = (const float*)d_in[21];
  const float* qpWo = (const float*)d_in[22]; const float* qpbo = (const float*)d_in[23];
  const float* fW1 = (const float*)d_in[24]; const float* fb1 = (const float*)d_in[25];
  const float* fW2 = (const float*)d_in[26]; const float* fb2 = (const float*)d_in[27];
  // d_in[28] = Qs — provably unused
  const float* gW = (const float*)d_in[29]; const float* gb = (const float*)d_in[30];
  const float* hW = (const float*)d_in[31]; const float* hb = (const float*)d_in[32];

  float* out = (float*)d_out;
  ushort* qbf  = (ushort*)d_ws;          // 4 MB  bf16 [B,H,S,8] (scaled by log2e/sqrt8)
  ushort* kbf  = qbf + NQKV;             // 4 MB  bf16 [B,H,S,8]
  ushort* vtbf = kbf + NQKV;             // 4 MB  bf16 [B,H,8,S]
  ushort* obf  = vtbf + NQKV;            // 4 MB  bf16 [B,H,S,8]
  float*  img  = (float*)(obf + NQKV);   // 8 MB  fp32 [B,S,E]

  const int L = 11;  // layers 0..10 are dead code
  k_ln_qkv<<<1024, 256, 0, stream>>>(x_path, ln_g, ln_b, cW, cb, qbf, kbf, vtbf);
  k_attn<<<1024, 512, 0, stream>>>(qbf, kbf, vtbf, obf);
  k_oproj<<<1024, 256, 0, stream>>>(obf, x_path, cWo, cbo, img);
  k_final<<<128, 256, 0, stream>>>(img, x_omic,
      oW0, ob0, oW1, ob1, oW2, ob2, oW3, ob3,
      qoW + L * 96 * 32, qob + L * 96, qoWo + L * 32 * 32, qobo + L * 32,
      qpW + L * 96 * 32, qpb + L * 96, qpWo + L * 32 * 32, qpbo + L * 32,
      fW1 + L * 32 * 32, fb1 + L * 32, fW2 + L * 32 * 32, fb2 + L * 32,
      gW, gb, hW, hb, out);
}

// Round 7
// 53.778 us; speedup vs baseline: 3.9256x; 1.3641x over previous
//
#include <hip/hip_runtime.h>
#include <hip/hip_bf16.h>

typedef __attribute__((ext_vector_type(8))) short short8;
typedef __attribute__((ext_vector_type(4))) float f32x4;

__device__ __forceinline__ float elu1(float x) { return x > 0.f ? x : expm1f(x); }
__device__ __forceinline__ unsigned pkbf(float a, float b) {
  return (unsigned)__bfloat16_as_ushort(__float2bfloat16(a)) |
         ((unsigned)__bfloat16_as_ushort(__float2bfloat16(b)) << 16);
}
// truncation pack (a -> low16, b -> high16); bias cancels in softmax ratio
__device__ __forceinline__ unsigned pk_trunc(float a, float b) {
  return (__float_as_uint(a) >> 16) | (__float_as_uint(b) & 0xffff0000u);
}
__device__ __forceinline__ short8 cvt8(float4 a, float4 b, float s) {
  uint4 u = { pkbf(a.x * s, a.y * s), pkbf(a.z * s, a.w * s),
              pkbf(b.x * s, b.y * s), pkbf(b.z * s, b.w * s) };
  union { uint4 u4; short8 s8; } c; c.u4 = u; return c.s8;
}

// ---------------------------------------------------------------------------
// K1 (fused): LN + QKV(head slice) + attention, one block per (b,h).
//   512 thr / 8 waves; wave owns 64 s-rows.
//   Staging: per 16-row group, LN in registers (lane (g,qr) owns row qr,
//   elems g*8..+7); ONE MFMA with combined A = [Wq rows | Wk rows] (head
//   slice, q pre-scaled by log2e/sqrt8) gives Q^T and K^T together; second
//   MFMA gives V^T.  Q/K written to LDS row-layout (packed uint2), V^T to
//   LDS [8][512].  Q/K/V never touch HBM.
//   Attention: round-6 body (dual per-wave P, shared K-reads, exp2 builtin,
//   row-sum free via ones-row d=8) looped over 2 q-pairs of 32 rows.
//   LDS 56KB -> exactly 2 blocks/CU, 512 blocks = one full pass.
// ---------------------------------------------------------------------------
__global__ __launch_bounds__(512, 4) void k_fattn(
    const float* __restrict__ xp, const float* __restrict__ ln_g, const float* __restrict__ ln_b,
    const float* __restrict__ Wqkv, const float* __restrict__ bqkv,
    ushort* __restrict__ obf)
{
  __shared__ ushort qlds[512 * 8];        // Q rows [s][d], 8KB
  __shared__ ushort klds[512 * 8];        // K rows [s][d], 8KB
  __shared__ ushort vts[8 * 512];         // V^T [d][s], 8KB
  __shared__ ushort ps[8][2][16 * 64];    // per-wave, per-qg P, swizzled, 32KB

  const float sc = 0.35355339059327373f * 1.4426950408889634f;  // 1/sqrt(8)*log2(e)
  int tid = threadIdx.x, w = tid >> 6, lane = tid & 63;
  int g = lane >> 4, qr = lane & 15;
  int bh = blockIdx.x, b = bh >> 2, h = bh & 3;
  const short8 z8 = {0, 0, 0, 0, 0, 0, 0, 0};

  // ---- weight fragments (once per block) ----
  // combined QK tile: A rows 0-7 = Wq[h*8+r]*sc, rows 8-15 = Wk[32+h*8+r]
  int wrow = (qr < 8) ? (h * 8 + qr) : (32 + h * 8 + qr - 8);
  float qsc = (qr < 8) ? sc : 1.f;
  const float4* wr = (const float4*)(Wqkv + wrow * 32 + g * 8);
  short8 wqk = cvt8(wr[0], wr[1], qsc);
  short8 wv = z8;
  if (qr < 8) {
    const float4* vr = (const float4*)(Wqkv + (64 + h * 8 + qr) * 32 + g * 8);
    wv = cvt8(vr[0], vr[1], 1.f);
  }
  f32x4 bqk, bv;
  #pragma unroll
  for (int r = 0; r < 4; ++r) {
    bqk[r] = (g < 2) ? bqkv[h * 8 + g * 4 + r] * sc : bqkv[32 + h * 8 + (g - 2) * 4 + r];
    bv[r]  = (g < 2) ? bqkv[64 + h * 8 + g * 4 + r] : 0.f;
  }
  const float4* lg4 = (const float4*)(ln_g + g * 8);
  const float4* lb4 = (const float4*)(ln_b + g * 8);
  float4 ga = lg4[0], gb2 = lg4[1], ba = lb4[0], bb2 = lb4[1];

  // ---- staging: 4 groups of 16 rows per wave ----
  #pragma unroll
  for (int i = 0; i < 4; ++i) {
    int rloc = w * 64 + i * 16 + qr;
    const float4* xr = (const float4*)(xp + (b * 512 + rloc) * 32 + g * 8);
    float4 x0 = xr[0], x1 = xr[1];
    float s1 = x0.x + x0.y + x0.z + x0.w + x1.x + x1.y + x1.z + x1.w;
    float s2 = x0.x*x0.x + x0.y*x0.y + x0.z*x0.z + x0.w*x0.w
             + x1.x*x1.x + x1.y*x1.y + x1.z*x1.z + x1.w*x1.w;
    s1 += __shfl_xor(s1, 16); s1 += __shfl_xor(s1, 32);
    s2 += __shfl_xor(s2, 16); s2 += __shfl_xor(s2, 32);
    float mu = s1 * 0.03125f;
    float rs = rsqrtf(s2 * 0.03125f - mu * mu + 1e-5f);
    float4 n0 = { (x0.x-mu)*rs*ga.x+ba.x, (x0.y-mu)*rs*ga.y+ba.y,
                  (x0.z-mu)*rs*ga.z+ba.z, (x0.w-mu)*rs*ga.w+ba.w };
    float4 n1 = { (x1.x-mu)*rs*gb2.x+bb2.x, (x1.y-mu)*rs*gb2.y+bb2.y,
                  (x1.z-mu)*rs*gb2.z+bb2.z, (x1.w-mu)*rs*gb2.w+bb2.w };
    short8 bx = cvt8(n0, n1, 1.f);   // B-frag: xn[s=qr][e=g*8+j]

    f32x4 cqk = __builtin_amdgcn_mfma_f32_16x16x32_bf16(wqk, bx, bqk, 0, 0, 0);
    f32x4 cv  = __builtin_amdgcn_mfma_f32_16x16x32_bf16(wv,  bx, bv,  0, 0, 0);
    // lane holds channels g*4+r (g<2: q 0-7; g>=2: k 0-7), col s=qr
    uint2 o2 = { pkbf(cqk[0], cqk[1]), pkbf(cqk[2], cqk[3]) };
    ushort* dst = (g < 2) ? qlds : klds;
    *(uint2*)(dst + rloc * 8 + (g & 1) * 4) = o2;
    if (g < 2) {
      #pragma unroll
      for (int r = 0; r < 4; ++r)
        vts[(g * 4 + r) * 512 + rloc] = __bfloat16_as_ushort(__float2bfloat16(cv[r]));
    }
  }
  __syncthreads();

  // ---- attention ----
  const short8 one8 = {(short)0x3F80, (short)0x3F80, (short)0x3F80, (short)0x3F80,
                       (short)0x3F80, (short)0x3F80, (short)0x3F80, (short)0x3F80};
  unsigned swz = (unsigned)(qr & 7) << 4;
  char* p0 = (char*)&ps[w][0][0] + qr * 128;
  char* p1 = (char*)&ps[w][1][0] + qr * 128;

  #pragma unroll
  for (int p = 0; p < 2; ++p) {
    int qbase = w * 64 + p * 32;
    short8 qf0 = (g == 0) ? *(const short8*)(qlds + (qbase + qr) * 8) : z8;
    short8 qf1 = (g == 0) ? *(const short8*)(qlds + (qbase + 16 + qr) * 8) : z8;
    f32x4 ot0 = {0.f, 0.f, 0.f, 0.f}, ot1 = {0.f, 0.f, 0.f, 0.f};

    for (int c = 0; c < 8; ++c) {
      const short8* vp = (const short8*)(vts + qr * 512 + c * 64 + g * 8);
      short8 vf0 = (qr < 8) ? vp[0] : (qr == 8 ? one8 : z8);
      short8 vf1 = (qr < 8) ? vp[4] : (qr == 8 ? one8 : z8);
      #pragma unroll
      for (int t = 0; t < 4; ++t) {
        short8 af = (g == 0) ? *(const short8*)(klds + (c * 64 + t * 16 + qr) * 8) : z8;
        f32x4 sa = __builtin_amdgcn_mfma_f32_16x16x32_bf16(af, qf0, (f32x4){0.f,0.f,0.f,0.f}, 0, 0, 0);
        f32x4 sb = __builtin_amdgcn_mfma_f32_16x16x32_bf16(af, qf1, (f32x4){0.f,0.f,0.f,0.f}, 0, 0, 0);
        unsigned off = (unsigned)((t * 16 + g * 4) << 1) ^ swz;
        uint2 pa = { pk_trunc(__builtin_amdgcn_exp2f(sa[0]), __builtin_amdgcn_exp2f(sa[1])),
                     pk_trunc(__builtin_amdgcn_exp2f(sa[2]), __builtin_amdgcn_exp2f(sa[3])) };
        uint2 pb2 = { pk_trunc(__builtin_amdgcn_exp2f(sb[0]), __builtin_amdgcn_exp2f(sb[1])),
                      pk_trunc(__builtin_amdgcn_exp2f(sb[2]), __builtin_amdgcn_exp2f(sb[3])) };
        *(uint2*)(p0 + off) = pa;
        *(uint2*)(p1 + off) = pb2;
      }
      #pragma unroll
      for (int tp = 0; tp < 2; ++tp) {
        unsigned off = (unsigned)((tp * 32 + g * 8) << 1) ^ swz;
        short8 vv = tp ? vf1 : vf0;
        short8 pba = *(const short8*)(p0 + off);
        short8 pbb = *(const short8*)(p1 + off);
        ot0 = __builtin_amdgcn_mfma_f32_16x16x32_bf16(vv, pba, ot0, 0, 0, 0);
        ot1 = __builtin_amdgcn_mfma_f32_16x16x32_bf16(vv, pbb, ot1, 0, 0, 0);
      }
    }
    // normalize + store: row-sum for qrow=qr sits in lane (g=2,qr) reg 0 (d=8)
    #pragma unroll
    for (int qg = 0; qg < 2; ++qg) {
      f32x4 ot = qg ? ot1 : ot0;
      float lpv = __shfl(ot[0], 32 + qr, 64);
      float rl = 1.f / lpv;
      if (g < 2) {
        int rowg = bh * 512 + qbase + qg * 16 + qr;
        uint2 o2 = { pkbf(ot[0] * rl, ot[1] * rl), pkbf(ot[2] * rl, ot[3] * rl) };
        *(uint2*)((unsigned*)obf + rowg * 4 + g * 2) = o2;
      }
    }
  }
}

// ---------------------------------------------------------------------------
// K2: oproj+residual into LDS (XOR-swizzled float4 slots, same involution on
//     write and both read passes), then the per-b tail.  Layers 0..10 are
//     dead code (qo-attention with a single key ignores its query input);
//     only layer 11 matters.  One block per b, 256 thr / 4 waves.
// ---------------------------------------------------------------------------
__global__ __launch_bounds__(256) void k_final(
    const ushort* __restrict__ obf, const float* __restrict__ xp,
    const float* __restrict__ Wo, const float* __restrict__ bo,
    const float* __restrict__ xo,
    const float* __restrict__ oW0, const float* __restrict__ ob0,
    const float* __restrict__ oW1, const float* __restrict__ ob1,
    const float* __restrict__ oW2, const float* __restrict__ ob2,
    const float* __restrict__ oW3, const float* __restrict__ ob3,
    const float* __restrict__ qoW, const float* __restrict__ qob,
    const float* __restrict__ qoWo, const float* __restrict__ qobo,
    const float* __restrict__ qpW, const float* __restrict__ qpb,
    const float* __restrict__ qpWo, const float* __restrict__ qpbo,
    const float* __restrict__ fW1, const float* __restrict__ fb1,
    const float* __restrict__ fW2, const float* __restrict__ fb2,
    const float* __restrict__ gW, const float* __restrict__ gb,
    const float* __restrict__ hW, const float* __restrict__ hb,
    float* __restrict__ out)
{
  __shared__ float4 imgl[512 * 8];   // img[b] in swizzled float4 slots, 64KB
  __shared__ float p[4][512];
  __shared__ float partial[8][4][32];
  __shared__ float buf1[80], buf2[64];
  __shared__ float emb[32], qbar[32], qh[32], u[4][32], cc4[4], lsum[4], ctx4[4][32], t32[32], o32[32];
  int b = blockIdx.x, tid = threadIdx.x;
  int w = tid >> 6, lane = tid & 63, g = lane >> 4, qr = lane & 15;

  // ---- oproj + residual -> imgl ----
  {
    short8 wa[2]; f32x4 bc2[2];
    #pragma unroll
    for (int t = 0; t < 2; ++t) {
      const float4* wrr = (const float4*)(Wo + (t * 16 + qr) * 32 + g * 8);
      wa[t] = cvt8(wrr[0], wrr[1], 1.f);
      const float4 bb = *(const float4*)(bo + t * 16 + g * 4);
      bc2[t] = (f32x4){bb.x, bb.y, bb.z, bb.w};
    }
    #pragma unroll
    for (int j = 0; j < 8; ++j) {
      int rloc = j * 64 + w * 16 + qr;
      short8 ob = *(const short8*)(obf + ((b * 4 + g) * 512 + rloc) * 8);
      #pragma unroll
      for (int t = 0; t < 2; ++t) {
        f32x4 ct = __builtin_amdgcn_mfma_f32_16x16x32_bf16(wa[t], ob, bc2[t], 0, 0, 0);
        int e4 = t * 4 + g;
        float4 xv = *(const float4*)(xp + (b * 512 + rloc) * 32 + e4 * 4);
        imgl[rloc * 8 + (e4 ^ (rloc & 7))] =
            (float4){ xv.x + ct[0], xv.y + ct[1], xv.z + ct[2], xv.w + ct[3] };
      }
    }
  }
  __syncthreads();

  // ---- frozen omic encoder ----
  if (tid < 80) buf1[tid] = xo[b * 80 + tid];
  __syncthreads();
  if (tid < 64) { float a = ob0[tid]; const float* wgt = oW0 + tid * 80;
    for (int e = 0; e < 80; ++e) a += buf1[e] * wgt[e]; buf2[tid] = elu1(a); }
  __syncthreads();
  if (tid < 48) { float a = ob1[tid]; const float* wgt = oW1 + tid * 64;
    for (int e = 0; e < 64; ++e) a += buf2[e] * wgt[e]; buf1[tid] = elu1(a); }
  __syncthreads();
  if (tid < 32) { float a = ob2[tid]; const float* wgt = oW2 + tid * 48;
    for (int e = 0; e < 48; ++e) a += buf1[e] * wgt[e]; buf2[tid] = elu1(a); }
  __syncthreads();
  if (tid < 32) { float a = ob3[tid]; const float* wgt = oW3 + tid * 32;
    for (int e = 0; e < 32; ++e) a += buf2[e] * wgt[e]; emb[tid] = elu1(a); }
  __syncthreads();

  // ---- qo attention (kv-len 1 => V,O proj only) ----
  if (tid < 32) { float a = qob[64 + tid]; const float* wgt = qoW + (64 + tid) * 32;
    for (int e = 0; e < 32; ++e) a += emb[e] * wgt[e]; t32[tid] = a; }
  __syncthreads();
  if (tid < 32) { float a = qobo[tid]; const float* wgt = qoWo + tid * 32;
    for (int e = 0; e < 32; ++e) a += t32[e] * wgt[e]; qbar[tid] = a; }
  __syncthreads();

  // ---- qp attention, single query row (folded) ----
  if (tid < 32) { float a = qpb[tid]; const float* wgt = qpW + tid * 32;
    for (int e = 0; e < 32; ++e) a += qbar[e] * wgt[e]; qh[tid] = a; }
  __syncthreads();
  if (tid < 128) {
    int hh = tid >> 5, e = tid & 31;
    float a = 0.f;
    #pragma unroll
    for (int d = 0; d < 8; ++d) a += qh[hh * 8 + d] * qpW[(32 + hh * 8 + d) * 32 + e];
    u[hh][e] = a;
    if (e == 0) { float c2 = 0.f; for (int d = 0; d < 8; ++d) c2 += qh[hh * 8 + d] * qpb[32 + hh * 8 + d]; cc4[hh] = c2; }
  }
  __syncthreads();

  #pragma unroll
  for (int j = 0; j < 8; ++j) {
    int idx = tid + j * 256; int hh = idx >> 9, kk = idx & 511;
    const float* uh = u[hh];
    float a = cc4[hh];
    #pragma unroll
    for (int e4 = 0; e4 < 8; ++e4) {
      float4 t = imgl[kk * 8 + (e4 ^ (kk & 7))];
      a += uh[e4 * 4] * t.x + uh[e4 * 4 + 1] * t.y + uh[e4 * 4 + 2] * t.z + uh[e4 * 4 + 3] * t.w;
    }
    p[hh][kk] = __builtin_amdgcn_exp2f(fminf(a * 0.51006979f, 115.f));
  }
  __syncthreads();
  {
    int ww = tid >> 6, ln2 = tid & 63;
    float a = 0.f;
    for (int kk = ln2; kk < 512; kk += 64) a += p[ww][kk];
    #pragma unroll
    for (int m = 32; m >= 1; m >>= 1) a += __shfl_xor(a, m, 64);
    if (ln2 == 0) lsum[ww] = 1.f / a;
  }
  {
    int e = tid & 31, ch = tid >> 5;
    float a0 = 0.f, a1 = 0.f, a2 = 0.f, a3 = 0.f;
    for (int kk = ch * 64; kk < ch * 64 + 64; ++kk) {
      float val = ((const float*)&imgl[kk * 8 + ((e >> 2) ^ (kk & 7))])[e & 3];
      a0 += p[0][kk] * val; a1 += p[1][kk] * val; a2 += p[2][kk] * val; a3 += p[3][kk] * val;
    }
    partial[ch][0][e] = a0; partial[ch][1][e] = a1; partial[ch][2][e] = a2; partial[ch][3][e] = a3;
  }
  __syncthreads();
  if (tid < 128) {
    int hh = tid >> 5, e = tid & 31;
    float a = 0.f;
    #pragma unroll
    for (int ch = 0; ch < 8; ++ch) a += partial[ch][hh][e];
    ctx4[hh][e] = a * lsum[hh];
  }
  __syncthreads();
  if (tid < 32) { int hh = tid >> 3;
    float a = qpb[64 + tid]; const float* wgt = qpW + (64 + tid) * 32;
    for (int e = 0; e < 32; ++e) a += ctx4[hh][e] * wgt[e]; o32[tid] = a; }
  __syncthreads();
  if (tid < 32) { float a = qpbo[tid]; const float* wgt = qpWo + tid * 32;
    for (int e = 0; e < 32; ++e) a += o32[e] * wgt[e]; t32[tid] = a; }
  __syncthreads();

  // ---- FFN (no residual) ----
  if (tid < 32) { float a = fb1[tid]; const float* wgt = fW1 + tid * 32;
    for (int e = 0; e < 32; ++e) a += t32[e] * wgt[e]; o32[tid] = fmaxf(a, 0.f); }
  __syncthreads();
  if (tid < 32) { float a = fb2[tid]; const float* wgt = fW2 + tid * 32;
    for (int e = 0; e < 32; ++e) a += o32[e] * wgt[e]; qbar[tid] = a; }
  __syncthreads();

  // ---- heads ----
  if (tid < 32) out[b * 32 + tid] = qbar[tid];
  if (tid == 0) {
    float g0 = gb[0], g1 = gb[1], g2 = gb[2];
    for (int e = 0; e < 32; ++e) { float f = qbar[e]; g0 += f * gW[e]; g1 += f * gW[32 + e]; g2 += f * gW[64 + e]; }
    float m = fmaxf(g0, fmaxf(g1, g2));
    float lse = m + logf(expf(g0 - m) + expf(g1 - m) + expf(g2 - m));
    float* og = out + 4096;
    og[b * 3 + 0] = g0 - lse; og[b * 3 + 1] = g1 - lse; og[b * 3 + 2] = g2 - lse;
    float hz = hb[0];
    for (int e = 0; e < 32; ++e) hz += qbar[e] * hW[e];
    out[4480 + b] = 1.f / (1.f + expf(-hz)) * 6.f - 3.f;
  }
}

extern "C" void kernel_launch(void* const* d_in, const int* in_sizes, int n_in,
                              void* d_out, int out_size, void* d_ws, size_t ws_size,
                              hipStream_t stream) {
  const float* x_omic = (const float*)d_in[0];
  const float* x_path = (const float*)d_in[1];
  const float* oW0 = (const float*)d_in[2];  const float* ob0 = (const float*)d_in[3];
  const float* oW1 = (const float*)d_in[4];  const float* ob1 = (const float*)d_in[5];
  const float* oW2 = (const float*)d_in[6];  const float* ob2 = (const float*)d_in[7];
  const float* oW3 = (const float*)d_in[8];  const float* ob3 = (const float*)d_in[9];
  const float* ln_g = (const float*)d_in[10]; const float* ln_b = (const float*)d_in[11];
  const float* cW  = (const float*)d_in[12]; const float* cb  = (const float*)d_in[13];
  const float* cWo = (const float*)d_in[14]; const float* cbo = (const float*)d_in[15];
  const float* qoW = (const float*)d_in[16]; const float* qob = (const float*)d_in[17];
  const float* qoWo = (const float*)d_in[18]; const float* qobo = (const float*)d_in[19];
  const float* qpW = (const float*)d_in[20]; const float* qpb = (const float*)d_in[21];
  const float* qpWo = (const float*)d_in[22]; const float* qpbo = (const float*)d_in[23];
  const float* fW1 = (const float*)d_in[24]; const float* fb1 = (const float*)d_in[25];
  const float* fW2 = (const float*)d_in[26]; const float* fb2 = (const float*)d_in[27];
  // d_in[28] = Qs — provably unused
  const float* gW = (const float*)d_in[29]; const float* gb = (const float*)d_in[30];
  const float* hW = (const float*)d_in[31]; const float* hb = (const float*)d_in[32];

  float* out = (float*)d_out;
  ushort* obf = (ushort*)d_ws;   // 4 MB bf16 [B,H,S,8] — only surviving intermediate

  const int L = 11;  // layers 0..10 are dead code
  k_fattn<<<512, 512, 0, stream>>>(x_path, ln_g, ln_b, cW, cb, obf);
  k_final<<<128, 256, 0, stream>>>(obf, x_path, cWo, cbo, x_omic,
      oW0, ob0, oW1, ob1, oW2, ob2, oW3, ob3,
      qoW + L * 96 * 32, qob + L * 96, qoWo + L * 32 * 32, qobo + L * 32,
      qpW + L * 96 * 32, qpb + L * 96, qpWo + L * 32 * 32, qpbo + L * 32,
      fW1 + L * 32 * 32, fb1 + L * 32, fW2 + L * 32 * 32, fb2 + L * 32,
      gW, gb, hW, hb, out);
}

// Round 8
// 49.775 us; speedup vs baseline: 4.2413x; 1.0804x over previous
//
#include <hip/hip_runtime.h>
#include <hip/hip_bf16.h>

typedef __attribute__((ext_vector_type(8))) short short8;
typedef __attribute__((ext_vector_type(4))) float f32x4;

__device__ __forceinline__ float elu1(float x) { return x > 0.f ? x : expm1f(x); }
__device__ __forceinline__ unsigned pkbf(float a, float b) {
  return (unsigned)__bfloat16_as_ushort(__float2bfloat16(a)) |
         ((unsigned)__bfloat16_as_ushort(__float2bfloat16(b)) << 16);
}
__device__ __forceinline__ short8 cvt8(float4 a, float4 b, float s) {
  uint4 u = { pkbf(a.x * s, a.y * s), pkbf(a.z * s, a.w * s),
              pkbf(b.x * s, b.y * s), pkbf(b.z * s, b.w * s) };
  union { uint4 u4; short8 s8; } c; c.u4 = u; return c.s8;
}
// truncation pack via v_perm_b32: dst = [a.b2, a.b3, b.b2, b.b3]
__device__ __forceinline__ unsigned pk_perm(float a, float b) {
  return __builtin_amdgcn_perm(__float_as_uint(b), __float_as_uint(a), 0x07060302u);
}

// ---------------------------------------------------------------------------
// K1 (fused): LN + QKV(head slice) + attention, one block per (b,h).
//   512 thr / 8 waves; wave owns 64 q-rows.  LDS 40KB (Q 8 + K 8 + V^T 8 +
//   P 16).  Hot loop: c-outer (8 chunks of 64 kidx); V-frags loaded once
//   per c; 4 q-groups sequential through ONE per-wave P buffer.
//   Broadcast-A trick: K A-frag read unconditionally by all lanes (Q B-frag
//   zeros at k>=8 kill the garbage); exp via raw v_exp_f32; trunc-pack via
//   v_perm_b32; row-sum free via ones-rows (qr>=8) of V^T A-frag.
// ---------------------------------------------------------------------------
__global__ __launch_bounds__(512, 4) void k_fattn(
    const float* __restrict__ xp, const float* __restrict__ ln_g, const float* __restrict__ ln_b,
    const float* __restrict__ Wqkv, const float* __restrict__ bqkv,
    ushort* __restrict__ obf)
{
  __shared__ ushort qlds[512 * 8];        // Q rows [s][d], 8KB
  __shared__ ushort klds[512 * 8];        // K rows [s][d], 8KB
  __shared__ ushort vts[8 * 512];         // V^T [d][s], 8KB
  __shared__ ushort ps[8][16 * 64];       // per-wave P [16 qrow][64 kidx], swizzled, 16KB

  const float sc = 0.35355339059327373f * 1.4426950408889634f;  // 1/sqrt(8)*log2(e)
  int tid = threadIdx.x, w = tid >> 6, lane = tid & 63;
  int g = lane >> 4, qr = lane & 15;
  int bh = blockIdx.x, b = bh >> 2, h = bh & 3;
  const short8 z8 = {0, 0, 0, 0, 0, 0, 0, 0};

  // ---- weight fragments (once per block) ----
  int wrow = (qr < 8) ? (h * 8 + qr) : (32 + h * 8 + qr - 8);
  float qsc = (qr < 8) ? sc : 1.f;
  const float4* wr = (const float4*)(Wqkv + wrow * 32 + g * 8);
  short8 wqk = cvt8(wr[0], wr[1], qsc);
  short8 wv = z8;
  if (qr < 8) {
    const float4* vr = (const float4*)(Wqkv + (64 + h * 8 + qr) * 32 + g * 8);
    wv = cvt8(vr[0], vr[1], 1.f);
  }
  f32x4 bqk, bv;
  #pragma unroll
  for (int r = 0; r < 4; ++r) {
    bqk[r] = (g < 2) ? bqkv[h * 8 + g * 4 + r] * sc : bqkv[32 + h * 8 + (g - 2) * 4 + r];
    bv[r]  = (g < 2) ? bqkv[64 + h * 8 + g * 4 + r] : 0.f;
  }
  const float4* lg4 = (const float4*)(ln_g + g * 8);
  const float4* lb4 = (const float4*)(ln_b + g * 8);
  float4 ga = lg4[0], gb2 = lg4[1], ba = lb4[0], bb2 = lb4[1];

  // ---- staging: 4 groups of 16 rows per wave ----
  #pragma unroll
  for (int i = 0; i < 4; ++i) {
    int rloc = w * 64 + i * 16 + qr;
    const float4* xr = (const float4*)(xp + (b * 512 + rloc) * 32 + g * 8);
    float4 x0 = xr[0], x1 = xr[1];
    float s1 = x0.x + x0.y + x0.z + x0.w + x1.x + x1.y + x1.z + x1.w;
    float s2 = x0.x*x0.x + x0.y*x0.y + x0.z*x0.z + x0.w*x0.w
             + x1.x*x1.x + x1.y*x1.y + x1.z*x1.z + x1.w*x1.w;
    s1 += __shfl_xor(s1, 16); s1 += __shfl_xor(s1, 32);
    s2 += __shfl_xor(s2, 16); s2 += __shfl_xor(s2, 32);
    float mu = s1 * 0.03125f;
    float rs = rsqrtf(s2 * 0.03125f - mu * mu + 1e-5f);
    float4 n0 = { (x0.x-mu)*rs*ga.x+ba.x, (x0.y-mu)*rs*ga.y+ba.y,
                  (x0.z-mu)*rs*ga.z+ba.z, (x0.w-mu)*rs*ga.w+ba.w };
    float4 n1 = { (x1.x-mu)*rs*gb2.x+bb2.x, (x1.y-mu)*rs*gb2.y+bb2.y,
                  (x1.z-mu)*rs*gb2.z+bb2.z, (x1.w-mu)*rs*gb2.w+bb2.w };
    short8 bx = cvt8(n0, n1, 1.f);   // B-frag: xn[s=qr][e=g*8+j]

    f32x4 cqk = __builtin_amdgcn_mfma_f32_16x16x32_bf16(wqk, bx, bqk, 0, 0, 0);
    f32x4 cv  = __builtin_amdgcn_mfma_f32_16x16x32_bf16(wv,  bx, bv,  0, 0, 0);
    uint2 o2 = { pkbf(cqk[0], cqk[1]), pkbf(cqk[2], cqk[3]) };
    ushort* dst = (g < 2) ? qlds : klds;
    *(uint2*)(dst + rloc * 8 + (g & 1) * 4) = o2;
    if (g < 2) {
      #pragma unroll
      for (int r = 0; r < 4; ++r)
        vts[(g * 4 + r) * 512 + rloc] = __bfloat16_as_ushort(__float2bfloat16(cv[r]));
    }
  }
  __syncthreads();

  // ---- attention ----
  const short8 one8 = {(short)0x3F80, (short)0x3F80, (short)0x3F80, (short)0x3F80,
                       (short)0x3F80, (short)0x3F80, (short)0x3F80, (short)0x3F80};
  unsigned swz = (unsigned)(qr & 7) << 4;
  char* pw = (char*)&ps[w][0] + qr * 128;

  int qbase = w * 64;
  short8 qf0 = (g == 0) ? *(const short8*)(qlds + (qbase + qr) * 8) : z8;
  short8 qf1 = (g == 0) ? *(const short8*)(qlds + (qbase + 16 + qr) * 8) : z8;
  short8 qf2 = (g == 0) ? *(const short8*)(qlds + (qbase + 32 + qr) * 8) : z8;
  short8 qf3 = (g == 0) ? *(const short8*)(qlds + (qbase + 48 + qr) * 8) : z8;
  f32x4 ot0 = {0.f,0.f,0.f,0.f}, ot1 = {0.f,0.f,0.f,0.f};
  f32x4 ot2 = {0.f,0.f,0.f,0.f}, ot3 = {0.f,0.f,0.f,0.f};

#define QKPV(QF, OT) do {                                                       \
    _Pragma("unroll")                                                           \
    for (int t = 0; t < 4; ++t) {                                               \
      short8 af = *(const short8*)(kbase + t * 128);  /* broadcast, no mask */  \
      f32x4 s4 = __builtin_amdgcn_mfma_f32_16x16x32_bf16(af, QF,                \
                   (f32x4){0.f,0.f,0.f,0.f}, 0, 0, 0);                          \
      unsigned off = (unsigned)((t * 16 + g * 4) << 1) ^ swz;                   \
      uint2 pk2 = { pk_perm(__builtin_amdgcn_exp2f(s4[0]),                      \
                            __builtin_amdgcn_exp2f(s4[1])),                     \
                    pk_perm(__builtin_amdgcn_exp2f(s4[2]),                      \
                            __builtin_amdgcn_exp2f(s4[3])) };                   \
      *(uint2*)(pw + off) = pk2;                                                \
    }                                                                           \
    {                                                                           \
      short8 pb0 = *(const short8*)(pw + ((unsigned)((g * 8) << 1) ^ swz));     \
      OT = __builtin_amdgcn_mfma_f32_16x16x32_bf16(vf0, pb0, OT, 0, 0, 0);      \
      short8 pb1 = *(const short8*)(pw + ((unsigned)((32 + g * 8) << 1) ^ swz));\
      OT = __builtin_amdgcn_mfma_f32_16x16x32_bf16(vf1, pb1, OT, 0, 0, 0);      \
    }                                                                           \
  } while (0)

  for (int c = 0; c < 8; ++c) {
    const short8* vp = (const short8*)(vts + qr * 512 + c * 64 + g * 8);
    short8 vf0 = (qr < 8) ? vp[0] : one8;   // rows 8-15 = ones (row 8 = sum; 9-15 unread)
    short8 vf1 = (qr < 8) ? vp[4] : one8;
    const ushort* kbase = klds + c * 64 * 8 + qr * 8;
    QKPV(qf0, ot0);
    QKPV(qf1, ot1);
    QKPV(qf2, ot2);
    QKPV(qf3, ot3);
  }
#undef QKPV

  // ---- normalize + store: row-sum for qrow=qr sits in lane (g=2,qr) reg 0 ----
  #pragma unroll
  for (int i = 0; i < 4; ++i) {
    f32x4 ot = (i == 0) ? ot0 : (i == 1) ? ot1 : (i == 2) ? ot2 : ot3;
    float lpv = __shfl(ot[0], 32 + qr, 64);
    float rl = 1.f / lpv;
    if (g < 2) {
      int rowg = bh * 512 + qbase + i * 16 + qr;
      uint2 o2 = { pkbf(ot[0] * rl, ot[1] * rl), pkbf(ot[2] * rl, ot[3] * rl) };
      *(uint2*)((unsigned*)obf + rowg * 4 + g * 2) = o2;
    }
  }
}

// ---------------------------------------------------------------------------
// K2: oproj+residual into LDS (XOR-swizzled float4 slots), then the per-b
//     tail.  Layers 0..10 are dead code (qo-attention with a single key
//     ignores its query input); only layer 11 matters.
//     One block per b, 512 thr / 8 waves.
// ---------------------------------------------------------------------------
__global__ __launch_bounds__(512) void k_final(
    const ushort* __restrict__ obf, const float* __restrict__ xp,
    const float* __restrict__ Wo, const float* __restrict__ bo,
    const float* __restrict__ xo,
    const float* __restrict__ oW0, const float* __restrict__ ob0,
    const float* __restrict__ oW1, const float* __restrict__ ob1,
    const float* __restrict__ oW2, const float* __restrict__ ob2,
    const float* __restrict__ oW3, const float* __restrict__ ob3,
    const float* __restrict__ qoW, const float* __restrict__ qob,
    const float* __restrict__ qoWo, const float* __restrict__ qobo,
    const float* __restrict__ qpW, const float* __restrict__ qpb,
    const float* __restrict__ qpWo, const float* __restrict__ qpbo,
    const float* __restrict__ fW1, const float* __restrict__ fb1,
    const float* __restrict__ fW2, const float* __restrict__ fb2,
    const float* __restrict__ gW, const float* __restrict__ gb,
    const float* __restrict__ hW, const float* __restrict__ hb,
    float* __restrict__ out)
{
  __shared__ float4 imgl[512 * 8];      // img[b] in swizzled float4 slots, 64KB
  __shared__ float p[4][512];
  __shared__ float partial[16][4][32];
  __shared__ float buf1[80], buf2[64];
  __shared__ float emb[32], qbar[32], qh[32], u[4][32], cc4[4], lsum[4], ctx4[4][32], t32[32], o32[32];
  int b = blockIdx.x, tid = threadIdx.x;
  int w = tid >> 6, lane = tid & 63, g = lane >> 4, qr = lane & 15;

  // ---- oproj + residual -> imgl (8 waves x 4 iters x 2 MFMAs) ----
  {
    short8 wa[2]; f32x4 bc2[2];
    #pragma unroll
    for (int t = 0; t < 2; ++t) {
      const float4* wrr = (const float4*)(Wo + (t * 16 + qr) * 32 + g * 8);
      wa[t] = cvt8(wrr[0], wrr[1], 1.f);
      const float4 bb = *(const float4*)(bo + t * 16 + g * 4);
      bc2[t] = (f32x4){bb.x, bb.y, bb.z, bb.w};
    }
    #pragma unroll
    for (int j = 0; j < 4; ++j) {
      int rloc = j * 128 + w * 16 + qr;
      short8 ob = *(const short8*)(obf + ((b * 4 + g) * 512 + rloc) * 8);
      #pragma unroll
      for (int t = 0; t < 2; ++t) {
        f32x4 ct = __builtin_amdgcn_mfma_f32_16x16x32_bf16(wa[t], ob, bc2[t], 0, 0, 0);
        int e4 = t * 4 + g;
        float4 xv = *(const float4*)(xp + (b * 512 + rloc) * 32 + e4 * 4);
        imgl[rloc * 8 + (e4 ^ (rloc & 7))] =
            (float4){ xv.x + ct[0], xv.y + ct[1], xv.z + ct[2], xv.w + ct[3] };
      }
    }
  }
  __syncthreads();

  // ---- frozen omic encoder ----
  if (tid < 80) buf1[tid] = xo[b * 80 + tid];
  __syncthreads();
  if (tid < 64) { float a = ob0[tid]; const float* wgt = oW0 + tid * 80;
    for (int e = 0; e < 80; ++e) a += buf1[e] * wgt[e]; buf2[tid] = elu1(a); }
  __syncthreads();
  if (tid < 48) { float a = ob1[tid]; const float* wgt = oW1 + tid * 64;
    for (int e = 0; e < 64; ++e) a += buf2[e] * wgt[e]; buf1[tid] = elu1(a); }
  __syncthreads();
  if (tid < 32) { float a = ob2[tid]; const float* wgt = oW2 + tid * 48;
    for (int e = 0; e < 48; ++e) a += buf1[e] * wgt[e]; buf2[tid] = elu1(a); }
  __syncthreads();
  if (tid < 32) { float a = ob3[tid]; const float* wgt = oW3 + tid * 32;
    for (int e = 0; e < 32; ++e) a += buf2[e] * wgt[e]; emb[tid] = elu1(a); }
  __syncthreads();

  // ---- qo attention (kv-len 1 => V,O proj only) ----
  if (tid < 32) { float a = qob[64 + tid]; const float* wgt = qoW + (64 + tid) * 32;
    for (int e = 0; e < 32; ++e) a += emb[e] * wgt[e]; t32[tid] = a; }
  __syncthreads();
  if (tid < 32) { float a = qobo[tid]; const float* wgt = qoWo + tid * 32;
    for (int e = 0; e < 32; ++e) a += t32[e] * wgt[e]; qbar[tid] = a; }
  __syncthreads();

  // ---- qp attention, single query row (folded) ----
  if (tid < 32) { float a = qpb[tid]; const float* wgt = qpW + tid * 32;
    for (int e = 0; e < 32; ++e) a += qbar[e] * wgt[e]; qh[tid] = a; }
  __syncthreads();
  if (tid < 128) {
    int hh = tid >> 5, e = tid & 31;
    float a = 0.f;
    #pragma unroll
    for (int d = 0; d < 8; ++d) a += qh[hh * 8 + d] * qpW[(32 + hh * 8 + d) * 32 + e];
    u[hh][e] = a;
    if (e == 0) { float c2 = 0.f; for (int d = 0; d < 8; ++d) c2 += qh[hh * 8 + d] * qpb[32 + hh * 8 + d]; cc4[hh] = c2; }
  }
  __syncthreads();

  #pragma unroll
  for (int j = 0; j < 4; ++j) {
    int idx = tid + j * 512; int hh = idx >> 9, kk = idx & 511;
    const float* uh = u[hh];
    float a = cc4[hh];
    #pragma unroll
    for (int e4 = 0; e4 < 8; ++e4) {
      float4 t = imgl[kk * 8 + (e4 ^ (kk & 7))];
      a += uh[e4 * 4] * t.x + uh[e4 * 4 + 1] * t.y + uh[e4 * 4 + 2] * t.z + uh[e4 * 4 + 3] * t.w;
    }
    p[hh][kk] = __builtin_amdgcn_exp2f(fminf(a * 0.51006979f, 115.f));
  }
  __syncthreads();
  if (tid < 256) {
    int ww = tid >> 6, ln2 = tid & 63;
    float a = 0.f;
    for (int kk = ln2; kk < 512; kk += 64) a += p[ww][kk];
    #pragma unroll
    for (int m = 32; m >= 1; m >>= 1) a += __shfl_xor(a, m, 64);
    if (ln2 == 0) lsum[ww] = 1.f / a;
  }
  {
    int e = tid & 31, ch = tid >> 5;     // 16 chunks of 32 kidx
    float a0 = 0.f, a1 = 0.f, a2 = 0.f, a3 = 0.f;
    for (int kk = ch * 32; kk < ch * 32 + 32; ++kk) {
      float val = ((const float*)&imgl[kk * 8 + ((e >> 2) ^ (kk & 7))])[e & 3];
      a0 += p[0][kk] * val; a1 += p[1][kk] * val; a2 += p[2][kk] * val; a3 += p[3][kk] * val;
    }
    partial[ch][0][e] = a0; partial[ch][1][e] = a1; partial[ch][2][e] = a2; partial[ch][3][e] = a3;
  }
  __syncthreads();
  if (tid < 128) {
    int hh = tid >> 5, e = tid & 31;
    float a = 0.f;
    #pragma unroll
    for (int ch = 0; ch < 16; ++ch) a += partial[ch][hh][e];
    ctx4[hh][e] = a * lsum[hh];
  }
  __syncthreads();
  if (tid < 32) { int hh = tid >> 3;
    float a = qpb[64 + tid]; const float* wgt = qpW + (64 + tid) * 32;
    for (int e = 0; e < 32; ++e) a += ctx4[hh][e] * wgt[e]; o32[tid] = a; }
  __syncthreads();
  if (tid < 32) { float a = qpbo[tid]; const float* wgt = qpWo + tid * 32;
    for (int e = 0; e < 32; ++e) a += o32[e] * wgt[e]; t32[tid] = a; }
  __syncthreads();

  // ---- FFN (no residual) ----
  if (tid < 32) { float a = fb1[tid]; const float* wgt = fW1 + tid * 32;
    for (int e = 0; e < 32; ++e) a += t32[e] * wgt[e]; o32[tid] = fmaxf(a, 0.f); }
  __syncthreads();
  if (tid < 32) { float a = fb2[tid]; const float* wgt = fW2 + tid * 32;
    for (int e = 0; e < 32; ++e) a += o32[e] * wgt[e]; qbar[tid] = a; }
  __syncthreads();

  // ---- heads ----
  if (tid < 32) out[b * 32 + tid] = qbar[tid];
  if (tid == 0) {
    float g0 = gb[0], g1 = gb[1], g2 = gb[2];
    for (int e = 0; e < 32; ++e) { float f = qbar[e]; g0 += f * gW[e]; g1 += f * gW[32 + e]; g2 += f * gW[64 + e]; }
    float m = fmaxf(g0, fmaxf(g1, g2));
    float lse = m + logf(expf(g0 - m) + expf(g1 - m) + expf(g2 - m));
    float* og = out + 4096;
    og[b * 3 + 0] = g0 - lse; og[b * 3 + 1] = g1 - lse; og[b * 3 + 2] = g2 - lse;
    float hz = hb[0];
    for (int e = 0; e < 32; ++e) hz += qbar[e] * hW[e];
    out[4480 + b] = 1.f / (1.f + expf(-hz)) * 6.f - 3.f;
  }
}

extern "C" void kernel_launch(void* const* d_in, const int* in_sizes, int n_in,
                              void* d_out, int out_size, void* d_ws, size_t ws_size,
                              hipStream_t stream) {
  const float* x_omic = (const float*)d_in[0];
  const float* x_path = (const float*)d_in[1];
  const float* oW0 = (const float*)d_in[2];  const float* ob0 = (const float*)d_in[3];
  const float* oW1 = (const float*)d_in[4];  const float* ob1 = (const float*)d_in[5];
  const float* oW2 = (const float*)d_in[6];  const float* ob2 = (const float*)d_in[7];
  const float* oW3 = (const float*)d_in[8];  const float* ob3 = (const float*)d_in[9];
  const float* ln_g = (const float*)d_in[10]; const float* ln_b = (const float*)d_in[11];
  const float* cW  = (const float*)d_in[12]; const float* cb  = (const float*)d_in[13];
  const float* cWo = (const float*)d_in[14]; const float* cbo = (const float*)d_in[15];
  const float* qoW = (const float*)d_in[16]; const float* qob = (const float*)d_in[17];
  const float* qoWo = (const float*)d_in[18]; const float* qobo = (const float*)d_in[19];
  const float* qpW = (const float*)d_in[20]; const float* qpb = (const float*)d_in[21];
  const float* qpWo = (const float*)d_in[22]; const float* qpbo = (const float*)d_in[23];
  const float* fW1 = (const float*)d_in[24]; const float* fb1 = (const float*)d_in[25];
  const float* fW2 = (const float*)d_in[26]; const float* fb2 = (const float*)d_in[27];
  // d_in[28] = Qs — provably unused
  const float* gW = (const float*)d_in[29]; const float* gb = (const float*)d_in[30];
  const float* hW = (const float*)d_in[31]; const float* hb = (const float*)d_in[32];

  float* out = (float*)d_out;
  ushort* obf = (ushort*)d_ws;   // 4 MB bf16 [B,H,S,8] — only surviving intermediate

  const int L = 11;  // layers 0..10 are dead code
  k_fattn<<<512, 512, 0, stream>>>(x_path, ln_g, ln_b, cW, cb, obf);
  k_final<<<128, 512, 0, stream>>>(obf, x_path, cWo, cbo, x_omic,
      oW0, ob0, oW1, ob1, oW2, ob2, oW3, ob3,
      qoW + L * 96 * 32, qob + L * 96, qoWo + L * 32 * 32, qobo + L * 32,
      qpW + L * 96 * 32, qpb + L * 96, qpWo + L * 32 * 32, qpbo + L * 32,
      fW1 + L * 32 * 32, fb1 + L * 32, fW2 + L * 32 * 32, fb2 + L * 32,
      gW, gb, hW, hb, out);
}